// Round 9
// baseline (667.031 us; speedup 1.0000x reference)
//
#include <hip/hip_runtime.h>
#include <stdint.h>

typedef unsigned int u32;
typedef unsigned long long u64;

#define M1 2654435761u
#define M2 2246822519u
#define M3 3266489917u
#define M4 668265263u
#define NUM_IT 5
#define PCHUNK 16384   // fallback chunk
#define HCH 65536      // chist chunk (16 subtiles of 4096)
#define TILE 4096      // partition tile (partA)
#define PBCH 4096      // partB chunk
#define SB 64          // super-buckets (4096 nodes each; 49 used)
#define CHB 33         // partB chunks per super
#define NKB 1024       // key buckets (top 10 bits)
#define KCH 4096       // khist chunk
#define SCH 8192       // scatter chunk

// ---------------- setup ----------------

__global__ void k_init(const int* __restrict__ x, int* __restrict__ colors,
                       u32* __restrict__ bcnt5, u32* __restrict__ bhist,
                       u32* __restrict__ cnt3, int n, int nbuck) {
    int i = blockIdx.x * blockDim.x + threadIdx.x;
    if (i < n) colors[i] = x[i];
    if (i < 2 * NUM_IT * NKB) bcnt5[i] = 0u;                    // bcnt5 + bcur5
    if (i >= 12288 && i < 12288 + nbuck) bhist[i - 12288] = 0u;
    if (i >= 16384 && i < 16384 + 48) cnt3[i - 16384] = 0u;
}

// fine-bucket edge histogram (row>>8) + per-4096-subtile super histogram (row>>12)
__global__ void k_chist(const int* __restrict__ row, u32* __restrict__ bhist,
                        u32* __restrict__ thist, int e, int nbuck) {
    __shared__ u32 fineh[1024];
    __shared__ u32 shist[16 * SB];
    int t = threadIdx.x;  // 1024
    fineh[t] = 0u;
    shist[t] = 0u;        // 16*64 == 1024
    __syncthreads();
    int c0 = blockIdx.x * HCH;
    int ce = c0 + HCH; if (ce > e) ce = e;
    int k = 0;
    for (int i = c0 + t; i < ce; i += 1024, ++k) {
        u32 r = (u32)row[i];
        atomicAdd(&fineh[r >> 8], 1u);
        atomicAdd(&shist[((k >> 2) << 6) | (r >> 12)], 1u);
    }
    __syncthreads();
    if (t < nbuck) {
        u32 v = fineh[t];
        if (v) atomicAdd(&bhist[t], v);
    }
    {
        int m = t >> 6;                     // subtile within chunk (0..15)
        if (c0 + m * TILE < e)
            thist[(size_t)(blockIdx.x * 16 + m) * SB + (t & 63)] = shist[t];
    }
}

// scan fine-bucket counts -> boffE/bcur; super offsets boffS
__global__ void k_cscan(const u32* __restrict__ bhist, u32* __restrict__ boffE,
                        u32* __restrict__ bcur, u32* __restrict__ boffS,
                        int nbuck, int nbS) {
    __shared__ u32 sh[256];
    u32 run = 0u;
    for (int base = 0; base < nbuck; base += 256) {
        int id = base + threadIdx.x;
        u32 x = (id < nbuck) ? bhist[id] : 0u;
        sh[threadIdx.x] = x;
        __syncthreads();
        for (int o = 1; o < 256; o <<= 1) {
            u32 t = (threadIdx.x >= (u32)o) ? sh[threadIdx.x - o] : 0u;
            __syncthreads();
            sh[threadIdx.x] += t;
            __syncthreads();
        }
        if (id < nbuck) {
            u32 excl = sh[threadIdx.x] - x + run;
            boffE[id] = excl;
            bcur[id] = excl;
            if ((id & 15) == 0) boffS[id >> 4] = excl;
        }
        u32 tot = sh[255];
        __syncthreads();
        run += tot;
    }
    if (threadIdx.x == 0) { boffE[nbuck] = run; boffS[nbS] = run; }
}

// per-super column scan of thist -> exact per-tile write base (NO atomics in partA)
__global__ void k_tscan(const u32* __restrict__ thist, const u32* __restrict__ boffS,
                        u32* __restrict__ tbase, int ntiles) {
    __shared__ u32 sh[256];
    int b = blockIdx.x;          // super bucket (grid = nbS)
    int t = threadIdx.x;
    u32 run = boffS[b];
    for (int base = 0; base < ntiles; base += 256) {
        int tile = base + t;
        u32 x = (tile < ntiles) ? thist[(size_t)tile * SB + b] : 0u;
        sh[t] = x;
        __syncthreads();
        for (int o = 1; o < 256; o <<= 1) {
            u32 y = (t >= o) ? sh[t - o] : 0u;
            __syncthreads();
            sh[t] += y;
            __syncthreads();
        }
        if (tile < ntiles) tbase[(size_t)tile * SB + b] = run + sh[t] - x;
        u32 tot = sh[255];
        __syncthreads();
        run += tot;
    }
}

// Pass A: single-pass LDS tile-reorder multisplit (hist comes free from thist)
__global__ void k_partA(const int* __restrict__ row, const int* __restrict__ col,
                        const u32* __restrict__ thist, const u32* __restrict__ tbase,
                        u32* __restrict__ adjt, int e) {
    __shared__ u32 vals[TILE];
    __shared__ unsigned char bkt[TILE];
    __shared__ u32 lbase[SB + 1], gbase[SB], cur[SB];
    int t = threadIdx.x;  // 256
    int c0 = blockIdx.x * TILE;
    int ce = c0 + TILE; if (ce > e) ce = e;
    if (t < SB) {
        gbase[t] = tbase[(size_t)blockIdx.x * SB + t];
        cur[t] = 0u;
        lbase[t] = thist[(size_t)blockIdx.x * SB + t];  // reuse as count first
    }
    __syncthreads();
    if (t == 0) {
        u32 run = 0u;
        for (int b = 0; b < SB; ++b) { u32 h = lbase[b]; lbase[b] = run; run += h; }
        lbase[SB] = run;
    }
    __syncthreads();
    for (int i = c0 + t; i < ce; i += 256) {
        u32 r = (u32)row[i];
        u32 s = r >> 12;
        u32 p = lbase[s] + atomicAdd(&cur[s], 1u);
        vals[p] = ((r & 4095u) << 18) | (u32)col[i];
        bkt[p] = (unsigned char)s;
    }
    __syncthreads();
    int cnt = ce - c0;
    for (int i = t; i < cnt; i += 256) {
        u32 b = (u32)bkt[i];
        adjt[gbase[b] + ((u32)i - lbase[b])] = vals[i];  // consecutive i -> coalesced
    }
}

// Pass B: LDS tile-reorder of each super-bucket chunk into its 16 fine buckets
__global__ void k_partB(const u32* __restrict__ adjt, const u32* __restrict__ boffS,
                        u32* __restrict__ ecur, u32* __restrict__ adj) {
    __shared__ u32 vals[PBCH];
    __shared__ u32 hist[16], lbase[17], gbase[16], cur[16];
    int s = blockIdx.x / CHB, c = blockIdx.x % CHB;
    u32 lo = boffS[s] + (u32)c * PBCH;
    u32 hi = boffS[s + 1];
    if (lo >= hi) return;
    if (hi > lo + PBCH) hi = lo + PBCH;
    int t = threadIdx.x;  // 256
    if (t < 16) hist[t] = 0u;
    __syncthreads();
    for (u32 i = lo + t; i < hi; i += 256)
        atomicAdd(&hist[(adjt[i] >> 26) & 15u], 1u);
    __syncthreads();
    if (t == 0) {
        u32 run = 0u;
        for (int b = 0; b < 16; ++b) { lbase[b] = run; run += hist[b]; }
        lbase[16] = run;
    }
    __syncthreads();
    if (t < 16) {
        u32 h = hist[t];
        gbase[t] = h ? atomicAdd(&ecur[s * 16 + t], h) : 0u;
        cur[t] = 0u;
    }
    __syncthreads();
    for (u32 i = lo + t; i < hi; i += 256) {
        u32 v = adjt[i];
        u32 b = (v >> 26) & 15u;
        vals[lbase[b] + atomicAdd(&cur[b], 1u)] = v;
    }
    __syncthreads();
    u32 cnt = hi - lo;
    for (u32 i = t; i < cnt; i += 256) {
        u32 v = vals[i];
        u32 b = (v >> 26) & 15u;
        adj[gbase[b] + (i - lbase[b])] = v & 0x03FFFFFFu;  // (row&255)<<18 | col
    }
}

// fallback single-level partition (only if ws too small)
__global__ void k_part(const int* __restrict__ row, const int* __restrict__ col,
                       u32* __restrict__ bcur, u32* __restrict__ adjp, int e, int nbuck) {
    __shared__ u32 hist[1024], base[1024], cur[1024];
    int c0 = blockIdx.x * PCHUNK;
    int cend = c0 + PCHUNK; if (cend > e) cend = e;
    for (int t = threadIdx.x; t < nbuck; t += 256) hist[t] = 0u;
    __syncthreads();
    for (int i = c0 + threadIdx.x; i < cend; i += 256)
        atomicAdd(&hist[((u32)row[i]) >> 8], 1u);
    __syncthreads();
    for (int t = threadIdx.x; t < nbuck; t += 256) {
        u32 h = hist[t];
        base[t] = h ? atomicAdd(&bcur[t], h) : 0u;
        cur[t] = 0u;
    }
    __syncthreads();
    for (int i = c0 + threadIdx.x; i < cend; i += 256) {
        u32 r = (u32)row[i];
        u32 b = r >> 8;
        u32 local = atomicAdd(&cur[b], 1u);
        adjp[base[b] + local] = ((r & 255u) << 18) | (u32)col[i];
    }
}

// ---------------- CSR: split (round-8 post-mortem) ----------------
// Old fused k_csr: 64KB LDS staging -> 2 blocks/CU, occupancy 14%, VALU 5%,
// HBM 11% -> latency-bound on nothing. Split:
//   k_csr1: hist + wave-shuffle scan (4 barriers, 1KB LDS) -> deg/start/lists
//   k_csr2: permute adj (bucket-order) -> adjn (node-major) with LDS cursors;
//           disjoint dst kills the in-place race the old buf existed for.
// Both run at full block residency (782 blocks all co-resident).
// lists entries PACKED u64: lo32 = start, hi32 = (min(deg,0x3FFF)<<18) | node.

__global__ void k_csr1(const u32* __restrict__ adj, const u32* __restrict__ boffE,
                       u32* __restrict__ deg, u32* __restrict__ start,
                       u64* __restrict__ lists, u32* __restrict__ cnt3, int n) {
    __shared__ u32 cnt[256];
    __shared__ u32 wsum[4];
    __shared__ u32 ch[3], cbase[3];
    int b = blockIdx.x;
    int v0 = b << 8;
    u32 bs = boffE[b], be = boffE[b + 1];
    int t = threadIdx.x;
    int lane = t & 63, w = t >> 6;
    cnt[t] = 0u;
    if (t < 3) ch[t] = 0u;
    __syncthreads();
    for (u32 i = bs + (u32)t; i < be; i += 256u)
        atomicAdd(&cnt[adj[i] >> 18], 1u);
    __syncthreads();
    u32 myc = cnt[t];
    u32 ps = myc;
#pragma unroll
    for (int o = 1; o < 64; o <<= 1) {
        u32 y = (u32)__shfl_up((int)ps, o, 64);
        if (lane >= o) ps += y;
    }
    if (lane == 63) wsum[w] = ps;
    __syncthreads();
    u32 wb = 0u;
    for (int j = 0; j < w; ++j) wb += wsum[j];
    u32 excl = wb + ps - myc;
    int v = v0 + t;
    u32 cls = 0u, crk = 0u;
    if (v < n) {
        deg[v] = myc;
        start[v] = bs + excl;
        cls = (myc <= 32u) ? 0u : ((myc <= 64u) ? 1u : 2u);
        crk = atomicAdd(&ch[cls], 1u);
    }
    __syncthreads();
    if (t < 3) cbase[t] = ch[t] ? atomicAdd(&cnt3[t * 16], ch[t]) : 0u;
    __syncthreads();
    if (v < n) {
        u32 dcl = myc > 0x3FFFu ? 0x3FFFu : myc;
        lists[cls * (size_t)n + cbase[cls] + crk] =
            ((u64)((dcl << 18) | (u32)v) << 32) | (u64)(bs + excl);
    }
}

__global__ void k_csr2(const u32* __restrict__ adj, const u32* __restrict__ boffE,
                       const u32* __restrict__ start, u32* __restrict__ adjn, int n) {
    __shared__ u32 cur[256];
    int b = blockIdx.x;
    int v0 = b << 8;
    u32 bs = boffE[b], be = boffE[b + 1];
    int t = threadIdx.x;
    int v = v0 + t;
    cur[t] = (v < n) ? start[v] : 0u;
    __syncthreads();
    for (u32 i = bs + (u32)t; i < be; i += 256u) {
        u32 p = adj[i];
        u32 q = atomicAdd(&cur[p >> 18], 1u);
        adjn[q] = p & 0x3FFFFu;
    }
}

// ---------------- hash: 4-elem/lane packed bitonic + packed lists ----------------
// k_hash is at its gather/issue floor (~48 µs; ILP, persistence, fat blocks,
// packing beyond 4 regs, chain-shortening all explored rounds 1-8).
// A (d<=32): 8 nodes/wave, 8 lanes/node. B (32<d<=64): 4 nodes/wave,
// 16 lanes/node. C (d>64): strided fallback. Reads node-major adjn.
// Hash math bit-identical (sentinel 0xFFFFFFFF -> (c+1)==0).

__device__ __forceinline__ void ce_reg(u32& a, u32& b, bool up) {
    u32 mn = a < b ? a : b, mx = a < b ? b : a;
    a = up ? mn : mx; b = up ? mx : mn;
}
__device__ __forceinline__ void ce_shf(u32& a, int o, bool tm) {
    u32 ot = (u32)__shfl_xor((int)a, o, 64);
    u32 mn = a < ot ? a : ot, mx = a < ot ? ot : a;
    a = tm ? mn : mx;
}
#define CE_SH4(o, tm) { ce_shf(c0, o, tm); ce_shf(c1, o, tm); ce_shf(c2, o, tm); ce_shf(c3, o, tm); }
#define CE_RG4(up)    { ce_reg(c0, c2, up); ce_reg(c1, c3, up); ce_reg(c0, c1, up); ce_reg(c2, c3, up); }

__global__ void k_hash(const int* __restrict__ colors, const u32* __restrict__ deg,
                       const u32* __restrict__ adj,
                       const u64* __restrict__ lists, const u32* __restrict__ cnt3,
                       u64* __restrict__ keys, int n) {
    int lane = threadIdx.x & 63;
    int wid = (int)((blockIdx.x * 256u + threadIdx.x) >> 6);
    u32 nA = cnt3[0], nBc = cnt3[16], nCc = cnt3[32];
    int octA = (int)((nA + 7u) >> 3);
    int quadB = (int)((nBc + 3u) >> 2);
    if (wid < octA) {
        // -------- A: 8 nodes/wave, 8 lanes/node, 32-slot sort --------
        int s = lane & 7;
        int li = 8 * wid + (lane >> 3);
        int node = -1;
        u32 c0 = 0xFFFFFFFFu, c1 = 0xFFFFFFFFu, c2 = 0xFFFFFFFFu, c3 = 0xFFFFFFFFu;
        u32 e0 = 4u * (u32)s;
        if (li < (int)nA) {
            u64 pk = lists[li];
            u32 st = (u32)pk;
            u32 hi = (u32)(pk >> 32);
            u32 d = hi >> 18;
            node = (int)(hi & 0x3FFFFu);
            if (e0 + 0u < d) c0 = (u32)colors[adj[st + e0 + 0u]];
            if (e0 + 1u < d) c1 = (u32)colors[adj[st + e0 + 1u]];
            if (e0 + 2u < d) c2 = (u32)colors[adj[st + e0 + 2u]];
            if (e0 + 3u < d) c3 = (u32)colors[adj[st + e0 + 3u]];
        }
        bool s1 = (s & 1) == 0, s2 = (s & 2) == 0, s4 = (s & 4) == 0;
        // k=2
        ce_reg(c0, c1, true); ce_reg(c2, c3, false);
        // k=4
        CE_RG4(s1)
        // k=8
        CE_SH4(1, s1 == s2)
        CE_RG4(s2)
        // k=16
        CE_SH4(2, s2 == s4)
        CE_SH4(1, s1 == s4)
        CE_RG4(s4)
        // k=32 (final ascending merge)
        CE_SH4(4, s4)
        CE_SH4(2, s2)
        CE_SH4(1, s1)
        CE_RG4(true)
        // hash: pos = e = 4s + r
        u32 a1 = e0 * M1, a3 = e0 * M3;
        u32 v = (c0 + 1u) * (a1 + M2)           + (c1 + 1u) * (a1 + 1u * M1 + M2)
              + (c2 + 1u) * (a1 + 2u * M1 + M2) + (c3 + 1u) * (a1 + 3u * M1 + M2);
        u32 w = (c0 + 1u) * (a3 + M4)           + (c1 + 1u) * (a3 + 1u * M3 + M4)
              + (c2 + 1u) * (a3 + 2u * M3 + M4) + (c3 + 1u) * (a3 + 3u * M3 + M4);
#pragma unroll
        for (int o = 1; o < 8; o <<= 1) {
            v += (u32)__shfl_xor((int)v, o, 64);
            w += (u32)__shfl_xor((int)w, o, 64);
        }
        if (s == 0 && node >= 0) {
            u32 own = (u32)colors[node] + 1u;
            keys[node] = ((u64)(v * M2 + own * M1) << 32) | (u64)(w * M4 + own * M3);
        }
    } else if (wid < octA + quadB) {
        // -------- B: 4 nodes/wave, 16 lanes/node, 64-slot sort --------
        int s = lane & 15;
        int li = 4 * (wid - octA) + (lane >> 4);
        int node = -1;
        u32 c0 = 0xFFFFFFFFu, c1 = 0xFFFFFFFFu, c2 = 0xFFFFFFFFu, c3 = 0xFFFFFFFFu;
        u32 e0 = 4u * (u32)s;
        if (li < (int)nBc) {
            u64 pk = lists[(size_t)n + (u32)li];
            u32 st = (u32)pk;
            u32 hi = (u32)(pk >> 32);
            u32 d = hi >> 18;
            node = (int)(hi & 0x3FFFFu);
            if (e0 + 0u < d) c0 = (u32)colors[adj[st + e0 + 0u]];
            if (e0 + 1u < d) c1 = (u32)colors[adj[st + e0 + 1u]];
            if (e0 + 2u < d) c2 = (u32)colors[adj[st + e0 + 2u]];
            if (e0 + 3u < d) c3 = (u32)colors[adj[st + e0 + 3u]];
        }
        bool s1 = (s & 1) == 0, s2 = (s & 2) == 0, s4 = (s & 4) == 0, s8 = (s & 8) == 0;
        // k=2
        ce_reg(c0, c1, true); ce_reg(c2, c3, false);
        // k=4
        CE_RG4(s1)
        // k=8
        CE_SH4(1, s1 == s2)
        CE_RG4(s2)
        // k=16
        CE_SH4(2, s2 == s4)
        CE_SH4(1, s1 == s4)
        CE_RG4(s4)
        // k=32
        CE_SH4(4, s4 == s8)
        CE_SH4(2, s2 == s8)
        CE_SH4(1, s1 == s8)
        CE_RG4(s8)
        // k=64 (final ascending merge)
        CE_SH4(8, s8)
        CE_SH4(4, s4)
        CE_SH4(2, s2)
        CE_SH4(1, s1)
        CE_RG4(true)
        u32 a1 = e0 * M1, a3 = e0 * M3;
        u32 v = (c0 + 1u) * (a1 + M2)           + (c1 + 1u) * (a1 + 1u * M1 + M2)
              + (c2 + 1u) * (a1 + 2u * M1 + M2) + (c3 + 1u) * (a1 + 3u * M1 + M2);
        u32 w = (c0 + 1u) * (a3 + M4)           + (c1 + 1u) * (a3 + 1u * M3 + M4)
              + (c2 + 1u) * (a3 + 2u * M3 + M4) + (c3 + 1u) * (a3 + 3u * M3 + M4);
#pragma unroll
        for (int o = 1; o < 16; o <<= 1) {
            v += (u32)__shfl_xor((int)v, o, 64);
            w += (u32)__shfl_xor((int)w, o, 64);
        }
        if (s == 0 && node >= 0) {
            u32 own = (u32)colors[node] + 1u;
            keys[node] = ((u64)(v * M2 + own * M1) << 32) | (u64)(w * M4 + own * M3);
        }
    } else if (wid < octA + quadB + (int)nCc) {
        // -------- C: d>64, strided O(d^2) fallback (rare) --------
        u64 pk = lists[2u * (size_t)n + (u32)(wid - octA - quadB)];
        int node = (int)((u32)(pk >> 32) & 0x3FFFFu);
        u32 st = (u32)pk;
        u32 d = deg[node];                   // exact degree (packed field clamps)
        u32 v = 0u, w = 0u;
        for (u32 i = (u32)lane; i < d; i += 64u) {
            u32 ci = (u32)colors[adj[st + i]];
            u32 pos = 0u;
            for (u32 j = 0; j < d; ++j) {
                u32 cj = (u32)colors[adj[st + j]];
                pos += (cj < ci) || (cj == ci && j < i);
            }
            v += (ci + 1u) * (pos * M1 + M2);
            w += (ci + 1u) * (pos * M3 + M4);
        }
        for (int o = 32; o > 0; o >>= 1) {
            v += (u32)__shfl_xor((int)v, o, 64);
            w += (u32)__shfl_xor((int)w, o, 64);
        }
        if (lane == 0) {
            u32 own = (u32)colors[node] + 1u;
            keys[node] = ((u64)(v * M2 + own * M1) << 32) | (u64)(w * M4 + own * M3);
        }
    }
}

// ---------------- relabel pipeline: 1024 key buckets, payload sort ----------------

// LDS-aggregated key histogram (one bulk flush per block, not per key)
__global__ void k_khist(const u64* __restrict__ keys, u32* __restrict__ bcnt, int n) {
    __shared__ u32 h[NKB];
    int t = threadIdx.x;  // 256
    for (int i = t; i < NKB; i += 256) h[i] = 0u;
    __syncthreads();
    int c0 = blockIdx.x * KCH;
    int ce = c0 + KCH; if (ce > n) ce = n;
    for (int i = c0 + t; i < ce; i += 256)
        atomicAdd(&h[(u32)(keys[i] >> 54)], 1u);
    __syncthreads();
    for (int i = t; i < NKB; i += 256) {
        u32 v = h[i];
        if (v) atomicAdd(&bcnt[i], v);
    }
}

// scatter (key, node-id) into buckets, LDS-aggregated ranks.
// Fused bscan: wave 0 shuffle-scans bcnt into LDS; block 0 publishes boff.
__global__ void k_scatter(const u64* __restrict__ keys, u64* __restrict__ out,
                          u32* __restrict__ nout, const u32* __restrict__ bcnt,
                          u32* __restrict__ cur, u32* __restrict__ boff, int n) {
    __shared__ u32 h[NKB], base[NKB], boffL[NKB];
    int t = threadIdx.x;  // 1024
    h[t] = 0u;
    if (t < 64) {
        u32 v[16]; u32 s = 0u;
#pragma unroll
        for (int i = 0; i < 16; ++i) { v[i] = bcnt[t * 16 + i]; s += v[i]; }
        u32 ps = s;
#pragma unroll
        for (int o = 1; o < 64; o <<= 1) {
            u32 y = (u32)__shfl_up((int)ps, o, 64);
            if (t >= o) ps += y;
        }
        u32 run = ps - s;
#pragma unroll
        for (int i = 0; i < 16; ++i) { boffL[t * 16 + i] = run; run += v[i]; }
    }
    __syncthreads();
    if (blockIdx.x == 0) {
        boff[t] = boffL[t];
        if (t == 0) boff[NKB] = boffL[NKB - 1] + bcnt[NKB - 1];
    }
    int c0 = blockIdx.x * SCH;
    u64 k[8]; u32 r[8];
#pragma unroll
    for (int i = 0; i < 8; ++i) {
        int id = c0 + t + i * 1024;
        if (id < n) { k[i] = keys[id]; r[i] = atomicAdd(&h[(u32)(k[i] >> 54)], 1u); }
    }
    __syncthreads();
    base[t] = boffL[t] + (h[t] ? atomicAdd(&cur[t], h[t]) : 0u);
    __syncthreads();
#pragma unroll
    for (int i = 0; i < 8; ++i) {
        int id = c0 + t + i * 1024;
        if (id < n) {
            u32 p = base[(u32)(k[i] >> 54)] + r[i];
            out[p] = k[i];
            nout[p] = (u32)id;
        }
    }
}

// Adaptive-width (256 or 512) bitonic key+payload sort per bucket + fused
// distinct scan. Buckets are Poisson(195): 256-slot network (36 stages, 1
// slot/thread) covers 99.998% of blocks at ~2.5x less work than fixed 512.
// Emits comb = (bucket<<16)|localD and permuted node ids. Ties share localD.
__global__ void k_bsort(u64* __restrict__ data, u32* __restrict__ nidx,
                        const u32* __restrict__ boff,
                        u32* __restrict__ comb, u32* __restrict__ dcount) {
    __shared__ u64 sh[512];
    __shared__ u32 pid[512];
    __shared__ u32 ts[256];
    int b = blockIdx.x;
    u32 lo = boff[b];
    int cnt = (int)(boff[b + 1] - lo);
    if (cnt > 512) cnt = 512;  // Poisson(195); >512 impossible
    int m = (cnt <= 256) ? 256 : 512;
    int t = threadIdx.x;
    for (int i = t; i < m; i += 256) {
        sh[i] = (i < cnt) ? data[lo + i] : ~0ULL;
        pid[i] = (i < cnt) ? nidx[lo + i] : 0u;
    }
    __syncthreads();
    for (int k = 2; k <= m; k <<= 1) {
        for (int j = k >> 1; j > 0; j >>= 1) {
            for (int e = t; e < m; e += 256) {
                int p = e ^ j;
                if (p > e) {
                    u64 a = sh[e], c = sh[p];
                    bool up = ((e & k) == 0);
                    if (up ? (a > c) : (a < c)) {
                        sh[e] = c; sh[p] = a;
                        u32 tp = pid[e]; pid[e] = pid[p]; pid[p] = tp;
                    }
                }
            }
            __syncthreads();
        }
    }
    int i0 = 2 * t, i1 = 2 * t + 1;
    u32 f0 = (i0 < cnt) ? ((i0 == 0) ? 1u : (sh[i0] != sh[i0 - 1] ? 1u : 0u)) : 0u;
    u32 f1 = (i1 < cnt) ? (sh[i1] != sh[i1 - 1] ? 1u : 0u) : 0u;
    u32 s2 = f0 + f1;
    ts[t] = s2;
    __syncthreads();
    for (int o = 1; o < 256; o <<= 1) {
        u32 x = (t >= o) ? ts[t - o] : 0u;
        __syncthreads();
        ts[t] += x;
        __syncthreads();
    }
    u32 excl = ts[t] - s2;
    u32 tag = (u32)b << 16;
    if (i0 < cnt) { nidx[lo + i0] = pid[i0]; comb[lo + i0] = tag | (excl + f0); }
    if (i1 < cnt) { nidx[lo + i1] = pid[i1]; comb[lo + i1] = tag | (excl + f0 + f1); }
    if (t == 255) dcount[b] = ts[255];
}

// relabel with fused dscan: wave 0 shuffle-scans dcount into LDS,
// then streams colors[nidx[i]].
__global__ void k_relabel(const u32* __restrict__ comb, const u32* __restrict__ nidx,
                          const u32* __restrict__ dcount, int* __restrict__ colors, int n) {
    __shared__ u32 dbaseL[NKB];
    int t = threadIdx.x;  // 256
    if (t < 64) {
        u32 v[16]; u32 s = 0u;
#pragma unroll
        for (int i = 0; i < 16; ++i) { v[i] = dcount[t * 16 + i]; s += v[i]; }
        u32 ps = s;
#pragma unroll
        for (int o = 1; o < 64; o <<= 1) {
            u32 y = (u32)__shfl_up((int)ps, o, 64);
            if (t >= o) ps += y;
        }
        u32 run = ps - s;
#pragma unroll
        for (int i = 0; i < 16; ++i) { dbaseL[t * 16 + i] = run; run += v[i]; }
    }
    __syncthreads();
    int i = blockIdx.x * 256 + t;
    if (i >= n) return;
    u32 c = comb[i];
    colors[nidx[i]] = (int)(dbaseL[c >> 16] + (c & 0xFFFFu) - 1u);
}

// ---------------- launch ----------------

extern "C" void kernel_launch(void* const* d_in, const int* in_sizes, int n_in,
                              void* d_out, int out_size, void* d_ws, size_t ws_size,
                              hipStream_t stream) {
    const int* x = (const int*)d_in[0];
    const int* ei = (const int*)d_in[1];
    const int N = in_sizes[0];
    const int E = in_sizes[1] / 2;
    const int* row = ei;
    const int* col = ei + E;
    int* colors = (int*)d_out;

    const int ntiles = (E + TILE - 1) / TILE;

    char* ws = (char*)d_ws;
    size_t off = 0;
#define WS_ALLOC(T, name, bytes) T name = (T)(ws + off); off += (((size_t)(bytes)) + 255) & ~(size_t)255;
    WS_ALLOC(u32*, deg, (size_t)N * 4)
    WS_ALLOC(u32*, start, (size_t)N * 4)
    WS_ALLOC(u32*, adj, (size_t)E * 4)
    WS_ALLOC(u64*, keys, (size_t)N * 8)
    WS_ALLOC(u64*, sorted, (size_t)N * 8)
    WS_ALLOC(u32*, nidx, (size_t)N * 4)
    WS_ALLOC(u32*, comb, (size_t)N * 4)
    WS_ALLOC(u64*, lists, (size_t)3 * N * 8)              // packed class lists (not aliased)
    WS_ALLOC(u32*, bcnt5, (size_t)2 * NUM_IT * NKB * 4)   // histograms + zero-based cursors
    WS_ALLOC(u32*, boff, (NKB + 1) * 4)
    WS_ALLOC(u32*, dcount, NKB * 4)
    WS_ALLOC(u32*, bhist, 1024 * 4)
    WS_ALLOC(u32*, boffE, 1025 * 4)
    WS_ALLOC(u32*, bcur, 1024 * 4)
    WS_ALLOC(u32*, boffS, (SB + 1) * 4)
    WS_ALLOC(u32*, cnt3, 48 * 4)
    WS_ALLOC(u32*, thist, (size_t)ntiles * SB * 4)
    WS_ALLOC(u32*, tbase, (size_t)ntiles * SB * 4)
    // tail: adjt (E u32). Partition scratch first, then reused by k_csr2 as
    // the node-major adjacency that k_hash reads.
    u32* adjt = (u32*)(ws + off);
    const bool two_level = (off + (size_t)E * 4 <= ws_size);
#undef WS_ALLOC

    const int nB = (N + 255) / 256;
    const int nbuck = (N + 255) >> 8;      // fine buckets (782)
    const int nbS = (nbuck + 15) >> 4;     // super-buckets (49)
    const int kB = (N + KCH - 1) / KCH;
    const int sBk = (N + SCH - 1) / SCH;

    // CSR build (+fused degree classification in k_csr1)
    k_init<<<nB, 256, 0, stream>>>(x, colors, bcnt5, bhist, cnt3, N, nbuck);
    k_chist<<<(E + HCH - 1) / HCH, 1024, 0, stream>>>(row, bhist, thist, E, nbuck);
    k_cscan<<<1, 256, 0, stream>>>(bhist, boffE, bcur, boffS, nbuck, nbS);
    if (two_level) {
        k_tscan<<<nbS, 256, 0, stream>>>(thist, boffS, tbase, ntiles);
        k_partA<<<ntiles, 256, 0, stream>>>(row, col, thist, tbase, adjt, E);
        k_partB<<<nbS * CHB, 256, 0, stream>>>(adjt, boffS, bcur, adj);
    } else {
        k_part<<<(E + PCHUNK - 1) / PCHUNK, 256, 0, stream>>>(row, col, bcur, adj, E, nbuck);
    }
    k_csr1<<<nbuck, 256, 0, stream>>>(adj, boffE, deg, start, lists, cnt3, N);
    k_csr2<<<nbuck, 256, 0, stream>>>(adj, boffE, start, adjt, N);

    for (int it = 0; it < NUM_IT; ++it) {
        u32* bcnt = bcnt5 + it * NKB;
        u32* bcur_it = bcnt5 + (NUM_IT + it) * NKB;
        k_hash<<<(N + 3) / 4, 256, 0, stream>>>(colors, deg, adjt, lists, cnt3, keys, N);
        k_khist<<<kB, 256, 0, stream>>>(keys, bcnt, N);
        k_scatter<<<sBk, 1024, 0, stream>>>(keys, sorted, nidx, bcnt, bcur_it, boff, N);
        k_bsort<<<NKB, 256, 0, stream>>>(sorted, nidx, boff, comb, dcount);
        k_relabel<<<nB, 256, 0, stream>>>(comb, nidx, dcount, colors, N);
    }
}

// Round 11
// 635.240 us; speedup vs baseline: 1.0500x; 1.0500x over previous
//
#include <hip/hip_runtime.h>
#include <stdint.h>

typedef unsigned int u32;
typedef unsigned long long u64;

#define M1 2654435761u
#define M2 2246822519u
#define M3 3266489917u
#define M4 668265263u
#define NUM_IT 5
#define PCHUNK 16384   // fallback chunk
#define HCH 65536      // chist chunk (16 subtiles of 4096)
#define TILE 4096      // partition tile (partA)
#define PBCH 4096      // partB chunk
#define CCAP 16384
#define SB 64          // super-buckets (4096 nodes each; 49 used)
#define CHB 33         // partB chunks per super
#define NKB 1024       // key buckets (top 10 bits)
#define KCH 4096       // khist chunk
#define SCH 8192       // scatter chunk

// ---------------- setup ----------------

__global__ void k_init(const int* __restrict__ x, int* __restrict__ colors,
                       u32* __restrict__ bcnt5, u32* __restrict__ bhist,
                       u32* __restrict__ cnt3, int n, int nbuck) {
    int i = blockIdx.x * blockDim.x + threadIdx.x;
    if (i < n) colors[i] = x[i];
    if (i < 2 * NUM_IT * NKB) bcnt5[i] = 0u;                    // bcnt5 + bcur5
    if (i >= 12288 && i < 12288 + nbuck) bhist[i - 12288] = 0u;
    if (i >= 16384 && i < 16384 + 48) cnt3[i - 16384] = 0u;
}

// fine-bucket edge histogram (row>>8) + per-4096-subtile super histogram (row>>12)
__global__ void k_chist(const int* __restrict__ row, u32* __restrict__ bhist,
                        u32* __restrict__ thist, int e, int nbuck) {
    __shared__ u32 fineh[1024];
    __shared__ u32 shist[16 * SB];
    int t = threadIdx.x;  // 1024
    fineh[t] = 0u;
    shist[t] = 0u;        // 16*64 == 1024
    __syncthreads();
    int c0 = blockIdx.x * HCH;
    int ce = c0 + HCH; if (ce > e) ce = e;
    int k = 0;
    for (int i = c0 + t; i < ce; i += 1024, ++k) {
        u32 r = (u32)row[i];
        atomicAdd(&fineh[r >> 8], 1u);
        atomicAdd(&shist[((k >> 2) << 6) | (r >> 12)], 1u);
    }
    __syncthreads();
    if (t < nbuck) {
        u32 v = fineh[t];
        if (v) atomicAdd(&bhist[t], v);
    }
    {
        int m = t >> 6;                     // subtile within chunk (0..15)
        if (c0 + m * TILE < e)
            thist[(size_t)(blockIdx.x * 16 + m) * SB + (t & 63)] = shist[t];
    }
}

// scan fine-bucket counts -> boffE/bcur; super offsets boffS
__global__ void k_cscan(const u32* __restrict__ bhist, u32* __restrict__ boffE,
                        u32* __restrict__ bcur, u32* __restrict__ boffS,
                        int nbuck, int nbS) {
    __shared__ u32 sh[256];
    u32 run = 0u;
    for (int base = 0; base < nbuck; base += 256) {
        int id = base + threadIdx.x;
        u32 x = (id < nbuck) ? bhist[id] : 0u;
        sh[threadIdx.x] = x;
        __syncthreads();
        for (int o = 1; o < 256; o <<= 1) {
            u32 t = (threadIdx.x >= (u32)o) ? sh[threadIdx.x - o] : 0u;
            __syncthreads();
            sh[threadIdx.x] += t;
            __syncthreads();
        }
        if (id < nbuck) {
            u32 excl = sh[threadIdx.x] - x + run;
            boffE[id] = excl;
            bcur[id] = excl;
            if ((id & 15) == 0) boffS[id >> 4] = excl;
        }
        u32 tot = sh[255];
        __syncthreads();
        run += tot;
    }
    if (threadIdx.x == 0) { boffE[nbuck] = run; boffS[nbS] = run; }
}

// per-super column scan of thist -> exact per-tile write base (NO atomics in partA)
__global__ void k_tscan(const u32* __restrict__ thist, const u32* __restrict__ boffS,
                        u32* __restrict__ tbase, int ntiles) {
    __shared__ u32 sh[256];
    int b = blockIdx.x;          // super bucket (grid = nbS)
    int t = threadIdx.x;
    u32 run = boffS[b];
    for (int base = 0; base < ntiles; base += 256) {
        int tile = base + t;
        u32 x = (tile < ntiles) ? thist[(size_t)tile * SB + b] : 0u;
        sh[t] = x;
        __syncthreads();
        for (int o = 1; o < 256; o <<= 1) {
            u32 y = (t >= o) ? sh[t - o] : 0u;
            __syncthreads();
            sh[t] += y;
            __syncthreads();
        }
        if (tile < ntiles) tbase[(size_t)tile * SB + b] = run + sh[t] - x;
        u32 tot = sh[255];
        __syncthreads();
        run += tot;
    }
}

// Pass A: single-pass LDS tile-reorder multisplit (hist comes free from thist)
__global__ void k_partA(const int* __restrict__ row, const int* __restrict__ col,
                        const u32* __restrict__ thist, const u32* __restrict__ tbase,
                        u32* __restrict__ adjt, int e) {
    __shared__ u32 vals[TILE];
    __shared__ unsigned char bkt[TILE];
    __shared__ u32 lbase[SB + 1], gbase[SB], cur[SB];
    int t = threadIdx.x;  // 256
    int c0 = blockIdx.x * TILE;
    int ce = c0 + TILE; if (ce > e) ce = e;
    if (t < SB) {
        gbase[t] = tbase[(size_t)blockIdx.x * SB + t];
        cur[t] = 0u;
        lbase[t] = thist[(size_t)blockIdx.x * SB + t];  // reuse as count first
    }
    __syncthreads();
    if (t == 0) {
        u32 run = 0u;
        for (int b = 0; b < SB; ++b) { u32 h = lbase[b]; lbase[b] = run; run += h; }
        lbase[SB] = run;
    }
    __syncthreads();
    for (int i = c0 + t; i < ce; i += 256) {
        u32 r = (u32)row[i];
        u32 s = r >> 12;
        u32 p = lbase[s] + atomicAdd(&cur[s], 1u);
        vals[p] = ((r & 4095u) << 18) | (u32)col[i];
        bkt[p] = (unsigned char)s;
    }
    __syncthreads();
    int cnt = ce - c0;
    for (int i = t; i < cnt; i += 256) {
        u32 b = (u32)bkt[i];
        adjt[gbase[b] + ((u32)i - lbase[b])] = vals[i];  // consecutive i -> coalesced
    }
}

// Pass B: LDS tile-reorder of each super-bucket chunk into its 16 fine buckets
__global__ void k_partB(const u32* __restrict__ adjt, const u32* __restrict__ boffS,
                        u32* __restrict__ ecur, u32* __restrict__ adj) {
    __shared__ u32 vals[PBCH];
    __shared__ u32 hist[16], lbase[17], gbase[16], cur[16];
    int s = blockIdx.x / CHB, c = blockIdx.x % CHB;
    u32 lo = boffS[s] + (u32)c * PBCH;
    u32 hi = boffS[s + 1];
    if (lo >= hi) return;
    if (hi > lo + PBCH) hi = lo + PBCH;
    int t = threadIdx.x;  // 256
    if (t < 16) hist[t] = 0u;
    __syncthreads();
    for (u32 i = lo + t; i < hi; i += 256)
        atomicAdd(&hist[(adjt[i] >> 26) & 15u], 1u);
    __syncthreads();
    if (t == 0) {
        u32 run = 0u;
        for (int b = 0; b < 16; ++b) { lbase[b] = run; run += hist[b]; }
        lbase[16] = run;
    }
    __syncthreads();
    if (t < 16) {
        u32 h = hist[t];
        gbase[t] = h ? atomicAdd(&ecur[s * 16 + t], h) : 0u;
        cur[t] = 0u;
    }
    __syncthreads();
    for (u32 i = lo + t; i < hi; i += 256) {
        u32 v = adjt[i];
        u32 b = (v >> 26) & 15u;
        vals[lbase[b] + atomicAdd(&cur[b], 1u)] = v;
    }
    __syncthreads();
    u32 cnt = hi - lo;
    for (u32 i = t; i < cnt; i += 256) {
        u32 v = vals[i];
        u32 b = (v >> 26) & 15u;
        adj[gbase[b] + (i - lbase[b])] = v & 0x03FFFFFFu;  // (row&255)<<18 | col
    }
}

// fallback single-level partition (only if ws too small)
__global__ void k_part(const int* __restrict__ row, const int* __restrict__ col,
                       u32* __restrict__ bcur, u32* __restrict__ adjp, int e, int nbuck) {
    __shared__ u32 hist[1024], base[1024], cur[1024];
    int c0 = blockIdx.x * PCHUNK;
    int cend = c0 + PCHUNK; if (cend > e) cend = e;
    for (int t = threadIdx.x; t < nbuck; t += 256) hist[t] = 0u;
    __syncthreads();
    for (int i = c0 + threadIdx.x; i < cend; i += 256)
        atomicAdd(&hist[((u32)row[i]) >> 8], 1u);
    __syncthreads();
    for (int t = threadIdx.x; t < nbuck; t += 256) {
        u32 h = hist[t];
        base[t] = h ? atomicAdd(&bcur[t], h) : 0u;
        cur[t] = 0u;
    }
    __syncthreads();
    for (int i = c0 + threadIdx.x; i < cend; i += 256) {
        u32 r = (u32)row[i];
        u32 b = r >> 8;
        u32 local = atomicAdd(&cur[b], 1u);
        adjp[base[b] + local] = ((r & 255u) << 18) | (u32)col[i];
    }
}

// ---------------- CSR: fused, 1024 threads (round-10 race FIXED) ----------------
// Round-9 split regressed: cold-destination scatter caused 7.4x write
// amplification (189 MB vs 29 MB in-place). Fused + in-place permute;
// occupancy via 1024-thread blocks: 2 blocks/CU x 16 waves = 32 waves/CU.
// Round-10 BUG: lists packed cur[t], racing with the permute loop's
// atomicAdd on cur (t>=256 threads pass the last barrier and bump cur
// before t<256 reads it). FIX: pack the register myStart = bs + excl.
__global__ void k_csr(u32* __restrict__ adj, const u32* __restrict__ boffE,
                      u32* __restrict__ deg, u32* __restrict__ start,
                      u64* __restrict__ lists, u32* __restrict__ cnt3, int n) {
    __shared__ u32 buf[CCAP];
    __shared__ u32 cnt[256], cur[256];
    __shared__ u32 wsum[4];
    __shared__ u32 ch[3], cbase[3];
    int b = blockIdx.x;
    int v0 = b << 8;
    u32 bs = boffE[b], be = boffE[b + 1];
    int c = (int)(be - bs);
    if (c > CCAP) c = CCAP;
    int t = threadIdx.x;  // 1024
    int lane = t & 63, w = t >> 6;
    if (t < 256) cnt[t] = 0u;
    if (t < 3) ch[t] = 0u;
    for (int i = t; i < c; i += 1024) buf[i] = adj[bs + i];
    __syncthreads();
    for (int i = t; i < c; i += 1024)
        atomicAdd(&cnt[buf[i] >> 18], 1u);
    __syncthreads();
    u32 myc = 0u, ps = 0u;
    if (t < 256) {
        myc = cnt[t];
        ps = myc;
#pragma unroll
        for (int o = 1; o < 64; o <<= 1) {
            u32 y = (u32)__shfl_up((int)ps, o, 64);
            if (lane >= o) ps += y;
        }
        if (lane == 63) wsum[w] = ps;
    }
    __syncthreads();
    u32 cls = 0u, crk = 0u, myStart = 0u;
    int v = v0 + t;
    if (t < 256) {
        u32 wb = 0u;
        for (int j = 0; j < w; ++j) wb += wsum[j];
        u32 excl = wb + ps - myc;
        myStart = bs + excl;
        if (v < n) {
            deg[v] = myc;
            start[v] = myStart;
            cls = (myc <= 32u) ? 0u : ((myc <= 64u) ? 1u : 2u);
            crk = atomicAdd(&ch[cls], 1u);
        }
        cur[t] = myStart;
    }
    __syncthreads();
    if (t < 3) cbase[t] = ch[t] ? atomicAdd(&cnt3[t * 16], ch[t]) : 0u;
    __syncthreads();
    if (t < 256 && v < n) {
        u32 dcl = myc > 0x3FFFu ? 0x3FFFu : myc;
        lists[cls * (size_t)n + cbase[cls] + crk] =
            ((u64)((dcl << 18) | (u32)v) << 32) | (u64)myStart;   // register — no race
    }
    for (int i = t; i < c; i += 1024) {
        u32 p = buf[i];
        u32 q = atomicAdd(&cur[p >> 18], 1u);
        adj[q] = p & 0x3FFFFu;   // in-place: lines L2-warm from staging read
    }
}

// ---------------- hash: 4-elem/lane packed bitonic + packed lists ----------------
// k_hash is at its gather/issue floor (~48 µs; ILP, persistence, fat blocks,
// packing beyond 4 regs, chain-shortening all explored rounds 1-8).
// A (d<=32): 8 nodes/wave, 8 lanes/node. B (32<d<=64): 4 nodes/wave,
// 16 lanes/node. C (d>64): strided fallback. Reads in-place-permuted adj.
// Hash math bit-identical (sentinel 0xFFFFFFFF -> (c+1)==0).

__device__ __forceinline__ void ce_reg(u32& a, u32& b, bool up) {
    u32 mn = a < b ? a : b, mx = a < b ? b : a;
    a = up ? mn : mx; b = up ? mx : mn;
}
__device__ __forceinline__ void ce_shf(u32& a, int o, bool tm) {
    u32 ot = (u32)__shfl_xor((int)a, o, 64);
    u32 mn = a < ot ? a : ot, mx = a < ot ? ot : a;
    a = tm ? mn : mx;
}
#define CE_SH4(o, tm) { ce_shf(c0, o, tm); ce_shf(c1, o, tm); ce_shf(c2, o, tm); ce_shf(c3, o, tm); }
#define CE_RG4(up)    { ce_reg(c0, c2, up); ce_reg(c1, c3, up); ce_reg(c0, c1, up); ce_reg(c2, c3, up); }

__global__ void k_hash(const int* __restrict__ colors, const u32* __restrict__ deg,
                       const u32* __restrict__ adj,
                       const u64* __restrict__ lists, const u32* __restrict__ cnt3,
                       u64* __restrict__ keys, int n) {
    int lane = threadIdx.x & 63;
    int wid = (int)((blockIdx.x * 256u + threadIdx.x) >> 6);
    u32 nA = cnt3[0], nBc = cnt3[16], nCc = cnt3[32];
    int octA = (int)((nA + 7u) >> 3);
    int quadB = (int)((nBc + 3u) >> 2);
    if (wid < octA) {
        // -------- A: 8 nodes/wave, 8 lanes/node, 32-slot sort --------
        int s = lane & 7;
        int li = 8 * wid + (lane >> 3);
        int node = -1;
        u32 c0 = 0xFFFFFFFFu, c1 = 0xFFFFFFFFu, c2 = 0xFFFFFFFFu, c3 = 0xFFFFFFFFu;
        u32 e0 = 4u * (u32)s;
        if (li < (int)nA) {
            u64 pk = lists[li];
            u32 st = (u32)pk;
            u32 hi = (u32)(pk >> 32);
            u32 d = hi >> 18;
            node = (int)(hi & 0x3FFFFu);
            if (e0 + 0u < d) c0 = (u32)colors[adj[st + e0 + 0u]];
            if (e0 + 1u < d) c1 = (u32)colors[adj[st + e0 + 1u]];
            if (e0 + 2u < d) c2 = (u32)colors[adj[st + e0 + 2u]];
            if (e0 + 3u < d) c3 = (u32)colors[adj[st + e0 + 3u]];
        }
        bool s1 = (s & 1) == 0, s2 = (s & 2) == 0, s4 = (s & 4) == 0;
        // k=2
        ce_reg(c0, c1, true); ce_reg(c2, c3, false);
        // k=4
        CE_RG4(s1)
        // k=8
        CE_SH4(1, s1 == s2)
        CE_RG4(s2)
        // k=16
        CE_SH4(2, s2 == s4)
        CE_SH4(1, s1 == s4)
        CE_RG4(s4)
        // k=32 (final ascending merge)
        CE_SH4(4, s4)
        CE_SH4(2, s2)
        CE_SH4(1, s1)
        CE_RG4(true)
        // hash: pos = e = 4s + r
        u32 a1 = e0 * M1, a3 = e0 * M3;
        u32 v = (c0 + 1u) * (a1 + M2)           + (c1 + 1u) * (a1 + 1u * M1 + M2)
              + (c2 + 1u) * (a1 + 2u * M1 + M2) + (c3 + 1u) * (a1 + 3u * M1 + M2);
        u32 w = (c0 + 1u) * (a3 + M4)           + (c1 + 1u) * (a3 + 1u * M3 + M4)
              + (c2 + 1u) * (a3 + 2u * M3 + M4) + (c3 + 1u) * (a3 + 3u * M3 + M4);
#pragma unroll
        for (int o = 1; o < 8; o <<= 1) {
            v += (u32)__shfl_xor((int)v, o, 64);
            w += (u32)__shfl_xor((int)w, o, 64);
        }
        if (s == 0 && node >= 0) {
            u32 own = (u32)colors[node] + 1u;
            keys[node] = ((u64)(v * M2 + own * M1) << 32) | (u64)(w * M4 + own * M3);
        }
    } else if (wid < octA + quadB) {
        // -------- B: 4 nodes/wave, 16 lanes/node, 64-slot sort --------
        int s = lane & 15;
        int li = 4 * (wid - octA) + (lane >> 4);
        int node = -1;
        u32 c0 = 0xFFFFFFFFu, c1 = 0xFFFFFFFFu, c2 = 0xFFFFFFFFu, c3 = 0xFFFFFFFFu;
        u32 e0 = 4u * (u32)s;
        if (li < (int)nBc) {
            u64 pk = lists[(size_t)n + (u32)li];
            u32 st = (u32)pk;
            u32 hi = (u32)(pk >> 32);
            u32 d = hi >> 18;
            node = (int)(hi & 0x3FFFFu);
            if (e0 + 0u < d) c0 = (u32)colors[adj[st + e0 + 0u]];
            if (e0 + 1u < d) c1 = (u32)colors[adj[st + e0 + 1u]];
            if (e0 + 2u < d) c2 = (u32)colors[adj[st + e0 + 2u]];
            if (e0 + 3u < d) c3 = (u32)colors[adj[st + e0 + 3u]];
        }
        bool s1 = (s & 1) == 0, s2 = (s & 2) == 0, s4 = (s & 4) == 0, s8 = (s & 8) == 0;
        // k=2
        ce_reg(c0, c1, true); ce_reg(c2, c3, false);
        // k=4
        CE_RG4(s1)
        // k=8
        CE_SH4(1, s1 == s2)
        CE_RG4(s2)
        // k=16
        CE_SH4(2, s2 == s4)
        CE_SH4(1, s1 == s4)
        CE_RG4(s4)
        // k=32
        CE_SH4(4, s4 == s8)
        CE_SH4(2, s2 == s8)
        CE_SH4(1, s1 == s8)
        CE_RG4(s8)
        // k=64 (final ascending merge)
        CE_SH4(8, s8)
        CE_SH4(4, s4)
        CE_SH4(2, s2)
        CE_SH4(1, s1)
        CE_RG4(true)
        u32 a1 = e0 * M1, a3 = e0 * M3;
        u32 v = (c0 + 1u) * (a1 + M2)           + (c1 + 1u) * (a1 + 1u * M1 + M2)
              + (c2 + 1u) * (a1 + 2u * M1 + M2) + (c3 + 1u) * (a1 + 3u * M1 + M2);
        u32 w = (c0 + 1u) * (a3 + M4)           + (c1 + 1u) * (a3 + 1u * M3 + M4)
              + (c2 + 1u) * (a3 + 2u * M3 + M4) + (c3 + 1u) * (a3 + 3u * M3 + M4);
#pragma unroll
        for (int o = 1; o < 16; o <<= 1) {
            v += (u32)__shfl_xor((int)v, o, 64);
            w += (u32)__shfl_xor((int)w, o, 64);
        }
        if (s == 0 && node >= 0) {
            u32 own = (u32)colors[node] + 1u;
            keys[node] = ((u64)(v * M2 + own * M1) << 32) | (u64)(w * M4 + own * M3);
        }
    } else if (wid < octA + quadB + (int)nCc) {
        // -------- C: d>64, strided O(d^2) fallback (rare) --------
        u64 pk = lists[2u * (size_t)n + (u32)(wid - octA - quadB)];
        int node = (int)((u32)(pk >> 32) & 0x3FFFFu);
        u32 st = (u32)pk;
        u32 d = deg[node];                   // exact degree (packed field clamps)
        u32 v = 0u, w = 0u;
        for (u32 i = (u32)lane; i < d; i += 64u) {
            u32 ci = (u32)colors[adj[st + i]];
            u32 pos = 0u;
            for (u32 j = 0; j < d; ++j) {
                u32 cj = (u32)colors[adj[st + j]];
                pos += (cj < ci) || (cj == ci && j < i);
            }
            v += (ci + 1u) * (pos * M1 + M2);
            w += (ci + 1u) * (pos * M3 + M4);
        }
        for (int o = 32; o > 0; o >>= 1) {
            v += (u32)__shfl_xor((int)v, o, 64);
            w += (u32)__shfl_xor((int)w, o, 64);
        }
        if (lane == 0) {
            u32 own = (u32)colors[node] + 1u;
            keys[node] = ((u64)(v * M2 + own * M1) << 32) | (u64)(w * M4 + own * M3);
        }
    }
}

// ---------------- relabel pipeline: 1024 key buckets, payload sort ----------------

// LDS-aggregated key histogram (one bulk flush per block, not per key)
__global__ void k_khist(const u64* __restrict__ keys, u32* __restrict__ bcnt, int n) {
    __shared__ u32 h[NKB];
    int t = threadIdx.x;  // 256
    for (int i = t; i < NKB; i += 256) h[i] = 0u;
    __syncthreads();
    int c0 = blockIdx.x * KCH;
    int ce = c0 + KCH; if (ce > n) ce = n;
    for (int i = c0 + t; i < ce; i += 256)
        atomicAdd(&h[(u32)(keys[i] >> 54)], 1u);
    __syncthreads();
    for (int i = t; i < NKB; i += 256) {
        u32 v = h[i];
        if (v) atomicAdd(&bcnt[i], v);
    }
}

// scatter (key, node-id) into buckets, LDS-aggregated ranks.
// Fused bscan: wave 0 shuffle-scans bcnt into LDS; block 0 publishes boff.
__global__ void k_scatter(const u64* __restrict__ keys, u64* __restrict__ out,
                          u32* __restrict__ nout, const u32* __restrict__ bcnt,
                          u32* __restrict__ cur, u32* __restrict__ boff, int n) {
    __shared__ u32 h[NKB], base[NKB], boffL[NKB];
    int t = threadIdx.x;  // 1024
    h[t] = 0u;
    if (t < 64) {
        u32 v[16]; u32 s = 0u;
#pragma unroll
        for (int i = 0; i < 16; ++i) { v[i] = bcnt[t * 16 + i]; s += v[i]; }
        u32 ps = s;
#pragma unroll
        for (int o = 1; o < 64; o <<= 1) {
            u32 y = (u32)__shfl_up((int)ps, o, 64);
            if (t >= o) ps += y;
        }
        u32 run = ps - s;
#pragma unroll
        for (int i = 0; i < 16; ++i) { boffL[t * 16 + i] = run; run += v[i]; }
    }
    __syncthreads();
    if (blockIdx.x == 0) {
        boff[t] = boffL[t];
        if (t == 0) boff[NKB] = boffL[NKB - 1] + bcnt[NKB - 1];
    }
    int c0 = blockIdx.x * SCH;
    u64 k[8]; u32 r[8];
#pragma unroll
    for (int i = 0; i < 8; ++i) {
        int id = c0 + t + i * 1024;
        if (id < n) { k[i] = keys[id]; r[i] = atomicAdd(&h[(u32)(k[i] >> 54)], 1u); }
    }
    __syncthreads();
    base[t] = boffL[t] + (h[t] ? atomicAdd(&cur[t], h[t]) : 0u);
    __syncthreads();
#pragma unroll
    for (int i = 0; i < 8; ++i) {
        int id = c0 + t + i * 1024;
        if (id < n) {
            u32 p = base[(u32)(k[i] >> 54)] + r[i];
            out[p] = k[i];
            nout[p] = (u32)id;
        }
    }
}

// Adaptive-width (256 or 512) bitonic key+payload sort per bucket + fused
// distinct scan. Buckets are Poisson(195): 256-slot network (36 stages, 1
// slot/thread) covers 99.998% of blocks at ~2.5x less work than fixed 512.
// Emits comb = (bucket<<16)|localD and permuted node ids. Ties share localD.
__global__ void k_bsort(u64* __restrict__ data, u32* __restrict__ nidx,
                        const u32* __restrict__ boff,
                        u32* __restrict__ comb, u32* __restrict__ dcount) {
    __shared__ u64 sh[512];
    __shared__ u32 pid[512];
    __shared__ u32 ts[256];
    int b = blockIdx.x;
    u32 lo = boff[b];
    int cnt = (int)(boff[b + 1] - lo);
    if (cnt > 512) cnt = 512;  // Poisson(195); >512 impossible
    int m = (cnt <= 256) ? 256 : 512;
    int t = threadIdx.x;
    for (int i = t; i < m; i += 256) {
        sh[i] = (i < cnt) ? data[lo + i] : ~0ULL;
        pid[i] = (i < cnt) ? nidx[lo + i] : 0u;
    }
    __syncthreads();
    for (int k = 2; k <= m; k <<= 1) {
        for (int j = k >> 1; j > 0; j >>= 1) {
            for (int e = t; e < m; e += 256) {
                int p = e ^ j;
                if (p > e) {
                    u64 a = sh[e], c = sh[p];
                    bool up = ((e & k) == 0);
                    if (up ? (a > c) : (a < c)) {
                        sh[e] = c; sh[p] = a;
                        u32 tp = pid[e]; pid[e] = pid[p]; pid[p] = tp;
                    }
                }
            }
            __syncthreads();
        }
    }
    int i0 = 2 * t, i1 = 2 * t + 1;
    u32 f0 = (i0 < cnt) ? ((i0 == 0) ? 1u : (sh[i0] != sh[i0 - 1] ? 1u : 0u)) : 0u;
    u32 f1 = (i1 < cnt) ? (sh[i1] != sh[i1 - 1] ? 1u : 0u) : 0u;
    u32 s2 = f0 + f1;
    ts[t] = s2;
    __syncthreads();
    for (int o = 1; o < 256; o <<= 1) {
        u32 x = (t >= o) ? ts[t - o] : 0u;
        __syncthreads();
        ts[t] += x;
        __syncthreads();
    }
    u32 excl = ts[t] - s2;
    u32 tag = (u32)b << 16;
    if (i0 < cnt) { nidx[lo + i0] = pid[i0]; comb[lo + i0] = tag | (excl + f0); }
    if (i1 < cnt) { nidx[lo + i1] = pid[i1]; comb[lo + i1] = tag | (excl + f0 + f1); }
    if (t == 255) dcount[b] = ts[255];
}

// relabel with fused dscan: wave 0 shuffle-scans dcount into LDS,
// then streams colors[nidx[i]].
__global__ void k_relabel(const u32* __restrict__ comb, const u32* __restrict__ nidx,
                          const u32* __restrict__ dcount, int* __restrict__ colors, int n) {
    __shared__ u32 dbaseL[NKB];
    int t = threadIdx.x;  // 256
    if (t < 64) {
        u32 v[16]; u32 s = 0u;
#pragma unroll
        for (int i = 0; i < 16; ++i) { v[i] = dcount[t * 16 + i]; s += v[i]; }
        u32 ps = s;
#pragma unroll
        for (int o = 1; o < 64; o <<= 1) {
            u32 y = (u32)__shfl_up((int)ps, o, 64);
            if (t >= o) ps += y;
        }
        u32 run = ps - s;
#pragma unroll
        for (int i = 0; i < 16; ++i) { dbaseL[t * 16 + i] = run; run += v[i]; }
    }
    __syncthreads();
    int i = blockIdx.x * 256 + t;
    if (i >= n) return;
    u32 c = comb[i];
    colors[nidx[i]] = (int)(dbaseL[c >> 16] + (c & 0xFFFFu) - 1u);
}

// ---------------- launch ----------------

extern "C" void kernel_launch(void* const* d_in, const int* in_sizes, int n_in,
                              void* d_out, int out_size, void* d_ws, size_t ws_size,
                              hipStream_t stream) {
    const int* x = (const int*)d_in[0];
    const int* ei = (const int*)d_in[1];
    const int N = in_sizes[0];
    const int E = in_sizes[1] / 2;
    const int* row = ei;
    const int* col = ei + E;
    int* colors = (int*)d_out;

    const int ntiles = (E + TILE - 1) / TILE;

    char* ws = (char*)d_ws;
    size_t off = 0;
#define WS_ALLOC(T, name, bytes) T name = (T)(ws + off); off += (((size_t)(bytes)) + 255) & ~(size_t)255;
    WS_ALLOC(u32*, deg, (size_t)N * 4)
    WS_ALLOC(u32*, start, (size_t)N * 4)
    WS_ALLOC(u32*, adj, (size_t)E * 4)
    WS_ALLOC(u64*, keys, (size_t)N * 8)
    WS_ALLOC(u64*, sorted, (size_t)N * 8)
    WS_ALLOC(u32*, nidx, (size_t)N * 4)
    WS_ALLOC(u32*, comb, (size_t)N * 4)
    WS_ALLOC(u64*, lists, (size_t)3 * N * 8)              // packed class lists (not aliased)
    WS_ALLOC(u32*, bcnt5, (size_t)2 * NUM_IT * NKB * 4)   // histograms + zero-based cursors
    WS_ALLOC(u32*, boff, (NKB + 1) * 4)
    WS_ALLOC(u32*, dcount, NKB * 4)
    WS_ALLOC(u32*, bhist, 1024 * 4)
    WS_ALLOC(u32*, boffE, 1025 * 4)
    WS_ALLOC(u32*, bcur, 1024 * 4)
    WS_ALLOC(u32*, boffS, (SB + 1) * 4)
    WS_ALLOC(u32*, cnt3, 48 * 4)
    WS_ALLOC(u32*, thist, (size_t)ntiles * SB * 4)
    WS_ALLOC(u32*, tbase, (size_t)ntiles * SB * 4)
    // tail: adjt (E u32), partition scratch only
    u32* adjt = (u32*)(ws + off);
    const bool two_level = (off + (size_t)E * 4 <= ws_size);
#undef WS_ALLOC

    const int nB = (N + 255) / 256;
    const int nbuck = (N + 255) >> 8;      // fine buckets (782)
    const int nbS = (nbuck + 15) >> 4;     // super-buckets (49)
    const int kB = (N + KCH - 1) / KCH;
    const int sBk = (N + SCH - 1) / SCH;

    // CSR build (+fused degree classification in k_csr)
    k_init<<<nB, 256, 0, stream>>>(x, colors, bcnt5, bhist, cnt3, N, nbuck);
    k_chist<<<(E + HCH - 1) / HCH, 1024, 0, stream>>>(row, bhist, thist, E, nbuck);
    k_cscan<<<1, 256, 0, stream>>>(bhist, boffE, bcur, boffS, nbuck, nbS);
    if (two_level) {
        k_tscan<<<nbS, 256, 0, stream>>>(thist, boffS, tbase, ntiles);
        k_partA<<<ntiles, 256, 0, stream>>>(row, col, thist, tbase, adjt, E);
        k_partB<<<nbS * CHB, 256, 0, stream>>>(adjt, boffS, bcur, adj);
    } else {
        k_part<<<(E + PCHUNK - 1) / PCHUNK, 256, 0, stream>>>(row, col, bcur, adj, E, nbuck);
    }
    k_csr<<<nbuck, 1024, 0, stream>>>(adj, boffE, deg, start, lists, cnt3, N);

    for (int it = 0; it < NUM_IT; ++it) {
        u32* bcnt = bcnt5 + it * NKB;
        u32* bcur_it = bcnt5 + (NUM_IT + it) * NKB;
        k_hash<<<(N + 3) / 4, 256, 0, stream>>>(colors, deg, adj, lists, cnt3, keys, N);
        k_khist<<<kB, 256, 0, stream>>>(keys, bcnt, N);
        k_scatter<<<sBk, 1024, 0, stream>>>(keys, sorted, nidx, bcnt, bcur_it, boff, N);
        k_bsort<<<NKB, 256, 0, stream>>>(sorted, nidx, boff, comb, dcount);
        k_relabel<<<nB, 256, 0, stream>>>(comb, nidx, dcount, colors, N);
    }
}

// Round 13
// 631.570 us; speedup vs baseline: 1.0561x; 1.0058x over previous
//
#include <hip/hip_runtime.h>
#include <stdint.h>

typedef unsigned int u32;
typedef unsigned long long u64;

#define M1 2654435761u
#define M2 2246822519u
#define M3 3266489917u
#define M4 668265263u
#define NUM_IT 5
#define PCHUNK 16384   // fallback chunk
#define HCH 65536      // chist chunk (16 subtiles of 4096)
#define TILE 4096      // partition tile (partA)
#define PBCH 4096      // partB chunk
#define CCAP 16384
#define SB 64          // super-buckets (4096 nodes each; 49 used)
#define CHB 33         // partB chunks per super
#define NKB 2048       // key buckets (top 11 bits; avg 97.7, P(>256)~0)
#define KSH 53         // key shift for bucket id
#define KCH 4096       // khist chunk
#define SCH 8192       // scatter chunk

// ---------------- setup ----------------

__global__ void k_init(const int* __restrict__ x, int* __restrict__ colors,
                       u32* __restrict__ bcnt5, u32* __restrict__ bhist,
                       u32* __restrict__ cnt3, int n, int nbuck) {
    int i = blockIdx.x * blockDim.x + threadIdx.x;
    if (i < n) colors[i] = x[i];
    if (i < 2 * NUM_IT * NKB) bcnt5[i] = 0u;                    // bcnt5 + bcur5 (20480)
    if (i >= 24576 && i < 24576 + nbuck) bhist[i - 24576] = 0u;
    if (i >= 32768 && i < 32768 + 48) cnt3[i - 32768] = 0u;
}

// fine-bucket edge histogram (row>>8) + per-4096-subtile super histogram (row>>12)
__global__ void k_chist(const int* __restrict__ row, u32* __restrict__ bhist,
                        u32* __restrict__ thist, int e, int nbuck) {
    __shared__ u32 fineh[1024];
    __shared__ u32 shist[16 * SB];
    int t = threadIdx.x;  // 1024
    fineh[t] = 0u;
    shist[t] = 0u;        // 16*64 == 1024
    __syncthreads();
    int c0 = blockIdx.x * HCH;
    int ce = c0 + HCH; if (ce > e) ce = e;
    int k = 0;
    for (int i = c0 + t; i < ce; i += 1024, ++k) {
        u32 r = (u32)row[i];
        atomicAdd(&fineh[r >> 8], 1u);
        atomicAdd(&shist[((k >> 2) << 6) | (r >> 12)], 1u);
    }
    __syncthreads();
    if (t < nbuck) {
        u32 v = fineh[t];
        if (v) atomicAdd(&bhist[t], v);
    }
    {
        int m = t >> 6;                     // subtile within chunk (0..15)
        if (c0 + m * TILE < e)
            thist[(size_t)(blockIdx.x * 16 + m) * SB + (t & 63)] = shist[t];
    }
}

// scan fine-bucket counts -> boffE/bcur; super offsets boffS
__global__ void k_cscan(const u32* __restrict__ bhist, u32* __restrict__ boffE,
                        u32* __restrict__ bcur, u32* __restrict__ boffS,
                        int nbuck, int nbS) {
    __shared__ u32 sh[256];
    u32 run = 0u;
    for (int base = 0; base < nbuck; base += 256) {
        int id = base + threadIdx.x;
        u32 x = (id < nbuck) ? bhist[id] : 0u;
        sh[threadIdx.x] = x;
        __syncthreads();
        for (int o = 1; o < 256; o <<= 1) {
            u32 t = (threadIdx.x >= (u32)o) ? sh[threadIdx.x - o] : 0u;
            __syncthreads();
            sh[threadIdx.x] += t;
            __syncthreads();
        }
        if (id < nbuck) {
            u32 excl = sh[threadIdx.x] - x + run;
            boffE[id] = excl;
            bcur[id] = excl;
            if ((id & 15) == 0) boffS[id >> 4] = excl;
        }
        u32 tot = sh[255];
        __syncthreads();
        run += tot;
    }
    if (threadIdx.x == 0) { boffE[nbuck] = run; boffS[nbS] = run; }
}

// per-super column scan of thist -> exact per-tile write base (NO atomics in partA)
__global__ void k_tscan(const u32* __restrict__ thist, const u32* __restrict__ boffS,
                        u32* __restrict__ tbase, int ntiles) {
    __shared__ u32 sh[256];
    int b = blockIdx.x;          // super bucket (grid = nbS)
    int t = threadIdx.x;
    u32 run = boffS[b];
    for (int base = 0; base < ntiles; base += 256) {
        int tile = base + t;
        u32 x = (tile < ntiles) ? thist[(size_t)tile * SB + b] : 0u;
        sh[t] = x;
        __syncthreads();
        for (int o = 1; o < 256; o <<= 1) {
            u32 y = (t >= o) ? sh[t - o] : 0u;
            __syncthreads();
            sh[t] += y;
            __syncthreads();
        }
        if (tile < ntiles) tbase[(size_t)tile * SB + b] = run + sh[t] - x;
        u32 tot = sh[255];
        __syncthreads();
        run += tot;
    }
}

// Pass A: single-pass LDS tile-reorder multisplit (hist comes free from thist)
__global__ void k_partA(const int* __restrict__ row, const int* __restrict__ col,
                        const u32* __restrict__ thist, const u32* __restrict__ tbase,
                        u32* __restrict__ adjt, int e) {
    __shared__ u32 vals[TILE];
    __shared__ unsigned char bkt[TILE];
    __shared__ u32 lbase[SB + 1], gbase[SB], cur[SB];
    int t = threadIdx.x;  // 256
    int c0 = blockIdx.x * TILE;
    int ce = c0 + TILE; if (ce > e) ce = e;
    if (t < SB) {
        gbase[t] = tbase[(size_t)blockIdx.x * SB + t];
        cur[t] = 0u;
        lbase[t] = thist[(size_t)blockIdx.x * SB + t];  // reuse as count first
    }
    __syncthreads();
    if (t == 0) {
        u32 run = 0u;
        for (int b = 0; b < SB; ++b) { u32 h = lbase[b]; lbase[b] = run; run += h; }
        lbase[SB] = run;
    }
    __syncthreads();
    for (int i = c0 + t; i < ce; i += 256) {
        u32 r = (u32)row[i];
        u32 s = r >> 12;
        u32 p = lbase[s] + atomicAdd(&cur[s], 1u);
        vals[p] = ((r & 4095u) << 18) | (u32)col[i];
        bkt[p] = (unsigned char)s;
    }
    __syncthreads();
    int cnt = ce - c0;
    for (int i = t; i < cnt; i += 256) {
        u32 b = (u32)bkt[i];
        adjt[gbase[b] + ((u32)i - lbase[b])] = vals[i];  // consecutive i -> coalesced
    }
}

// Pass B: LDS tile-reorder of each super-bucket chunk into its 16 fine buckets
__global__ void k_partB(const u32* __restrict__ adjt, const u32* __restrict__ boffS,
                        u32* __restrict__ ecur, u32* __restrict__ adj) {
    __shared__ u32 vals[PBCH];
    __shared__ u32 hist[16], lbase[17], gbase[16], cur[16];
    int s = blockIdx.x / CHB, c = blockIdx.x % CHB;
    u32 lo = boffS[s] + (u32)c * PBCH;
    u32 hi = boffS[s + 1];
    if (lo >= hi) return;
    if (hi > lo + PBCH) hi = lo + PBCH;
    int t = threadIdx.x;  // 256
    if (t < 16) hist[t] = 0u;
    __syncthreads();
    for (u32 i = lo + t; i < hi; i += 256)
        atomicAdd(&hist[(adjt[i] >> 26) & 15u], 1u);
    __syncthreads();
    if (t == 0) {
        u32 run = 0u;
        for (int b = 0; b < 16; ++b) { lbase[b] = run; run += hist[b]; }
        lbase[16] = run;
    }
    __syncthreads();
    if (t < 16) {
        u32 h = hist[t];
        gbase[t] = h ? atomicAdd(&ecur[s * 16 + t], h) : 0u;
        cur[t] = 0u;
    }
    __syncthreads();
    for (u32 i = lo + t; i < hi; i += 256) {
        u32 v = adjt[i];
        u32 b = (v >> 26) & 15u;
        vals[lbase[b] + atomicAdd(&cur[b], 1u)] = v;
    }
    __syncthreads();
    u32 cnt = hi - lo;
    for (u32 i = t; i < cnt; i += 256) {
        u32 v = vals[i];
        u32 b = (v >> 26) & 15u;
        adj[gbase[b] + (i - lbase[b])] = v & 0x03FFFFFFu;  // (row&255)<<18 | col
    }
}

// fallback single-level partition (only if ws too small)
__global__ void k_part(const int* __restrict__ row, const int* __restrict__ col,
                       u32* __restrict__ bcur, u32* __restrict__ adjp, int e, int nbuck) {
    __shared__ u32 hist[1024], base[1024], cur[1024];
    int c0 = blockIdx.x * PCHUNK;
    int cend = c0 + PCHUNK; if (cend > e) cend = e;
    for (int t = threadIdx.x; t < nbuck; t += 256) hist[t] = 0u;
    __syncthreads();
    for (int i = c0 + threadIdx.x; i < cend; i += 256)
        atomicAdd(&hist[((u32)row[i]) >> 8], 1u);
    __syncthreads();
    for (int t = threadIdx.x; t < nbuck; t += 256) {
        u32 h = hist[t];
        base[t] = h ? atomicAdd(&bcur[t], h) : 0u;
        cur[t] = 0u;
    }
    __syncthreads();
    for (int i = c0 + threadIdx.x; i < cend; i += 256) {
        u32 r = (u32)row[i];
        u32 b = r >> 8;
        u32 local = atomicAdd(&cur[b], 1u);
        adjp[base[b] + local] = ((r & 255u) << 18) | (u32)col[i];
    }
}

// ---------------- CSR: fused, 1024 threads, in-place permute ----------------
// Scattered-4B floor (~48 µs) resists occupancy (14%->52% same time, r11),
// split (write-amp 7.4x, r9), and chain-shortening. Parked.
__global__ void k_csr(u32* __restrict__ adj, const u32* __restrict__ boffE,
                      u32* __restrict__ deg, u32* __restrict__ start,
                      u64* __restrict__ lists, u32* __restrict__ cnt3, int n) {
    __shared__ u32 buf[CCAP];
    __shared__ u32 cnt[256], cur[256];
    __shared__ u32 wsum[4];
    __shared__ u32 ch[3], cbase[3];
    int b = blockIdx.x;
    int v0 = b << 8;
    u32 bs = boffE[b], be = boffE[b + 1];
    int c = (int)(be - bs);
    if (c > CCAP) c = CCAP;
    int t = threadIdx.x;  // 1024
    int lane = t & 63, w = t >> 6;
    if (t < 256) cnt[t] = 0u;
    if (t < 3) ch[t] = 0u;
    for (int i = t; i < c; i += 1024) buf[i] = adj[bs + i];
    __syncthreads();
    for (int i = t; i < c; i += 1024)
        atomicAdd(&cnt[buf[i] >> 18], 1u);
    __syncthreads();
    u32 myc = 0u, ps = 0u;
    if (t < 256) {
        myc = cnt[t];
        ps = myc;
#pragma unroll
        for (int o = 1; o < 64; o <<= 1) {
            u32 y = (u32)__shfl_up((int)ps, o, 64);
            if (lane >= o) ps += y;
        }
        if (lane == 63) wsum[w] = ps;
    }
    __syncthreads();
    u32 cls = 0u, crk = 0u, myStart = 0u;
    int v = v0 + t;
    if (t < 256) {
        u32 wb = 0u;
        for (int j = 0; j < w; ++j) wb += wsum[j];
        u32 excl = wb + ps - myc;
        myStart = bs + excl;
        if (v < n) {
            deg[v] = myc;
            start[v] = myStart;
            cls = (myc <= 32u) ? 0u : ((myc <= 64u) ? 1u : 2u);
            crk = atomicAdd(&ch[cls], 1u);
        }
        cur[t] = myStart;
    }
    __syncthreads();
    if (t < 3) cbase[t] = ch[t] ? atomicAdd(&cnt3[t * 16], ch[t]) : 0u;
    __syncthreads();
    if (t < 256 && v < n) {
        u32 dcl = myc > 0x3FFFu ? 0x3FFFu : myc;
        lists[cls * (size_t)n + cbase[cls] + crk] =
            ((u64)((dcl << 18) | (u32)v) << 32) | (u64)myStart;   // register — no race
    }
    for (int i = t; i < c; i += 1024) {
        u32 p = buf[i];
        u32 q = atomicAdd(&cur[p >> 18], 1u);
        adj[q] = p & 0x3FFFFu;   // in-place: lines L2-warm from staging read
    }
}

// ---------------- hash: 4-elem/lane packed bitonic + packed lists ----------------
// At its gather/issue floor (~48 µs; rounds 1-8 explored ILP, persistence,
// fat blocks, reg-packing, chain-shortening). Parked.

__device__ __forceinline__ void ce_reg(u32& a, u32& b, bool up) {
    u32 mn = a < b ? a : b, mx = a < b ? b : a;
    a = up ? mn : mx; b = up ? mx : mn;
}
__device__ __forceinline__ void ce_shf(u32& a, int o, bool tm) {
    u32 ot = (u32)__shfl_xor((int)a, o, 64);
    u32 mn = a < ot ? a : ot, mx = a < ot ? ot : a;
    a = tm ? mn : mx;
}
#define CE_SH4(o, tm) { ce_shf(c0, o, tm); ce_shf(c1, o, tm); ce_shf(c2, o, tm); ce_shf(c3, o, tm); }
#define CE_RG4(up)    { ce_reg(c0, c2, up); ce_reg(c1, c3, up); ce_reg(c0, c1, up); ce_reg(c2, c3, up); }

__global__ void k_hash(const int* __restrict__ colors, const u32* __restrict__ deg,
                       const u32* __restrict__ adj,
                       const u64* __restrict__ lists, const u32* __restrict__ cnt3,
                       u64* __restrict__ keys, int n) {
    int lane = threadIdx.x & 63;
    int wid = (int)((blockIdx.x * 256u + threadIdx.x) >> 6);
    u32 nA = cnt3[0], nBc = cnt3[16], nCc = cnt3[32];
    int octA = (int)((nA + 7u) >> 3);
    int quadB = (int)((nBc + 3u) >> 2);
    if (wid < octA) {
        // -------- A: 8 nodes/wave, 8 lanes/node, 32-slot sort --------
        int s = lane & 7;
        int li = 8 * wid + (lane >> 3);
        int node = -1;
        u32 c0 = 0xFFFFFFFFu, c1 = 0xFFFFFFFFu, c2 = 0xFFFFFFFFu, c3 = 0xFFFFFFFFu;
        u32 e0 = 4u * (u32)s;
        if (li < (int)nA) {
            u64 pk = lists[li];
            u32 st = (u32)pk;
            u32 hi = (u32)(pk >> 32);
            u32 d = hi >> 18;
            node = (int)(hi & 0x3FFFFu);
            if (e0 + 0u < d) c0 = (u32)colors[adj[st + e0 + 0u]];
            if (e0 + 1u < d) c1 = (u32)colors[adj[st + e0 + 1u]];
            if (e0 + 2u < d) c2 = (u32)colors[adj[st + e0 + 2u]];
            if (e0 + 3u < d) c3 = (u32)colors[adj[st + e0 + 3u]];
        }
        bool s1 = (s & 1) == 0, s2 = (s & 2) == 0, s4 = (s & 4) == 0;
        // k=2
        ce_reg(c0, c1, true); ce_reg(c2, c3, false);
        // k=4
        CE_RG4(s1)
        // k=8
        CE_SH4(1, s1 == s2)
        CE_RG4(s2)
        // k=16
        CE_SH4(2, s2 == s4)
        CE_SH4(1, s1 == s4)
        CE_RG4(s4)
        // k=32 (final ascending merge)
        CE_SH4(4, s4)
        CE_SH4(2, s2)
        CE_SH4(1, s1)
        CE_RG4(true)
        // hash: pos = e = 4s + r
        u32 a1 = e0 * M1, a3 = e0 * M3;
        u32 v = (c0 + 1u) * (a1 + M2)           + (c1 + 1u) * (a1 + 1u * M1 + M2)
              + (c2 + 1u) * (a1 + 2u * M1 + M2) + (c3 + 1u) * (a1 + 3u * M1 + M2);
        u32 w = (c0 + 1u) * (a3 + M4)           + (c1 + 1u) * (a3 + 1u * M3 + M4)
              + (c2 + 1u) * (a3 + 2u * M3 + M4) + (c3 + 1u) * (a3 + 3u * M3 + M4);
#pragma unroll
        for (int o = 1; o < 8; o <<= 1) {
            v += (u32)__shfl_xor((int)v, o, 64);
            w += (u32)__shfl_xor((int)w, o, 64);
        }
        if (s == 0 && node >= 0) {
            u32 own = (u32)colors[node] + 1u;
            keys[node] = ((u64)(v * M2 + own * M1) << 32) | (u64)(w * M4 + own * M3);
        }
    } else if (wid < octA + quadB) {
        // -------- B: 4 nodes/wave, 16 lanes/node, 64-slot sort --------
        int s = lane & 15;
        int li = 4 * (wid - octA) + (lane >> 4);
        int node = -1;
        u32 c0 = 0xFFFFFFFFu, c1 = 0xFFFFFFFFu, c2 = 0xFFFFFFFFu, c3 = 0xFFFFFFFFu;
        u32 e0 = 4u * (u32)s;
        if (li < (int)nBc) {
            u64 pk = lists[(size_t)n + (u32)li];
            u32 st = (u32)pk;
            u32 hi = (u32)(pk >> 32);
            u32 d = hi >> 18;
            node = (int)(hi & 0x3FFFFu);
            if (e0 + 0u < d) c0 = (u32)colors[adj[st + e0 + 0u]];
            if (e0 + 1u < d) c1 = (u32)colors[adj[st + e0 + 1u]];
            if (e0 + 2u < d) c2 = (u32)colors[adj[st + e0 + 2u]];
            if (e0 + 3u < d) c3 = (u32)colors[adj[st + e0 + 3u]];
        }
        bool s1 = (s & 1) == 0, s2 = (s & 2) == 0, s4 = (s & 4) == 0, s8 = (s & 8) == 0;
        // k=2
        ce_reg(c0, c1, true); ce_reg(c2, c3, false);
        // k=4
        CE_RG4(s1)
        // k=8
        CE_SH4(1, s1 == s2)
        CE_RG4(s2)
        // k=16
        CE_SH4(2, s2 == s4)
        CE_SH4(1, s1 == s4)
        CE_RG4(s4)
        // k=32
        CE_SH4(4, s4 == s8)
        CE_SH4(2, s2 == s8)
        CE_SH4(1, s1 == s8)
        CE_RG4(s8)
        // k=64 (final ascending merge)
        CE_SH4(8, s8)
        CE_SH4(4, s4)
        CE_SH4(2, s2)
        CE_SH4(1, s1)
        CE_RG4(true)
        u32 a1 = e0 * M1, a3 = e0 * M3;
        u32 v = (c0 + 1u) * (a1 + M2)           + (c1 + 1u) * (a1 + 1u * M1 + M2)
              + (c2 + 1u) * (a1 + 2u * M1 + M2) + (c3 + 1u) * (a1 + 3u * M1 + M2);
        u32 w = (c0 + 1u) * (a3 + M4)           + (c1 + 1u) * (a3 + 1u * M3 + M4)
              + (c2 + 1u) * (a3 + 2u * M3 + M4) + (c3 + 1u) * (a3 + 3u * M3 + M4);
#pragma unroll
        for (int o = 1; o < 16; o <<= 1) {
            v += (u32)__shfl_xor((int)v, o, 64);
            w += (u32)__shfl_xor((int)w, o, 64);
        }
        if (s == 0 && node >= 0) {
            u32 own = (u32)colors[node] + 1u;
            keys[node] = ((u64)(v * M2 + own * M1) << 32) | (u64)(w * M4 + own * M3);
        }
    } else if (wid < octA + quadB + (int)nCc) {
        // -------- C: d>64, strided O(d^2) fallback (rare) --------
        u64 pk = lists[2u * (size_t)n + (u32)(wid - octA - quadB)];
        int node = (int)((u32)(pk >> 32) & 0x3FFFFu);
        u32 st = (u32)pk;
        u32 d = deg[node];                   // exact degree (packed field clamps)
        u32 v = 0u, w = 0u;
        for (u32 i = (u32)lane; i < d; i += 64u) {
            u32 ci = (u32)colors[adj[st + i]];
            u32 pos = 0u;
            for (u32 j = 0; j < d; ++j) {
                u32 cj = (u32)colors[adj[st + j]];
                pos += (cj < ci) || (cj == ci && j < i);
            }
            v += (ci + 1u) * (pos * M1 + M2);
            w += (ci + 1u) * (pos * M3 + M4);
        }
        for (int o = 32; o > 0; o >>= 1) {
            v += (u32)__shfl_xor((int)v, o, 64);
            w += (u32)__shfl_xor((int)w, o, 64);
        }
        if (lane == 0) {
            u32 own = (u32)colors[node] + 1u;
            keys[node] = ((u64)(v * M2 + own * M1) << 32) | (u64)(w * M4 + own * M3);
        }
    }
}

// ---------------- relabel pipeline: 2048 key buckets, payload sort ----------------

// LDS-aggregated key histogram (one bulk flush per block, not per key)
__global__ void k_khist(const u64* __restrict__ keys, u32* __restrict__ bcnt, int n) {
    __shared__ u32 h[NKB];
    int t = threadIdx.x;  // 256
    for (int i = t; i < NKB; i += 256) h[i] = 0u;
    __syncthreads();
    int c0 = blockIdx.x * KCH;
    int ce = c0 + KCH; if (ce > n) ce = n;
    for (int i = c0 + t; i < ce; i += 256)
        atomicAdd(&h[(u32)(keys[i] >> KSH)], 1u);
    __syncthreads();
    for (int i = t; i < NKB; i += 256) {
        u32 v = h[i];
        if (v) atomicAdd(&bcnt[i], v);
    }
}

// scatter (key, node-id) into buckets, LDS-aggregated ranks.
// Fused bscan: wave 0 shuffle-scans bcnt (32/lane) into LDS; block 0
// publishes boff for k_bsort.
__global__ void k_scatter(const u64* __restrict__ keys, u64* __restrict__ out,
                          u32* __restrict__ nout, const u32* __restrict__ bcnt,
                          u32* __restrict__ cur, u32* __restrict__ boff, int n) {
    __shared__ u32 h[NKB], base[NKB], boffL[NKB];
    int t = threadIdx.x;  // 1024
    h[t] = 0u; h[t + 1024] = 0u;
    if (t < 64) {
        u32 v[32]; u32 s = 0u;
#pragma unroll
        for (int i = 0; i < 32; ++i) { v[i] = bcnt[t * 32 + i]; s += v[i]; }
        u32 ps = s;
#pragma unroll
        for (int o = 1; o < 64; o <<= 1) {
            u32 y = (u32)__shfl_up((int)ps, o, 64);
            if (t >= o) ps += y;
        }
        u32 run = ps - s;
#pragma unroll
        for (int i = 0; i < 32; ++i) { boffL[t * 32 + i] = run; run += v[i]; }
    }
    __syncthreads();
    if (blockIdx.x == 0) {
        boff[t] = boffL[t];
        boff[t + 1024] = boffL[t + 1024];
        if (t == 0) boff[NKB] = boffL[NKB - 1] + bcnt[NKB - 1];
    }
    int c0 = blockIdx.x * SCH;
    u64 k[8]; u32 r[8];
#pragma unroll
    for (int i = 0; i < 8; ++i) {
        int id = c0 + t + i * 1024;
        if (id < n) { k[i] = keys[id]; r[i] = atomicAdd(&h[(u32)(k[i] >> KSH)], 1u); }
    }
    __syncthreads();
    base[t] = boffL[t] + (h[t] ? atomicAdd(&cur[t], h[t]) : 0u);
    base[t + 1024] = boffL[t + 1024] + (h[t + 1024] ? atomicAdd(&cur[t + 1024], h[t + 1024]) : 0u);
    __syncthreads();
#pragma unroll
    for (int i = 0; i < 8; ++i) {
        int id = c0 + t + i * 1024;
        if (id < n) {
            u32 p = base[(u32)(k[i] >> KSH)] + r[i];
            out[p] = k[i];
            nout[p] = (u32)id;
        }
    }
}

// Adaptive-width (128 or 256) bitonic key+payload sort per bucket + fused
// distinct scan. Buckets are Poisson(97.7): 128-slot network (28 stages)
// covers nearly all blocks; 256 fallback (P(>256) ~ 16 sigma ~ 0).
// Emits comb = (bucket<<16)|localD and permuted node ids. Ties share localD.
__global__ void k_bsort(u64* __restrict__ data, u32* __restrict__ nidx,
                        const u32* __restrict__ boff,
                        u32* __restrict__ comb, u32* __restrict__ dcount) {
    __shared__ u64 sh[256];
    __shared__ u32 pid[256];
    __shared__ u32 ts[256];
    int b = blockIdx.x;
    u32 lo = boff[b];
    int cnt = (int)(boff[b + 1] - lo);
    if (cnt > 256) cnt = 256;  // Poisson(97.7); >256 impossible
    int m = (cnt <= 128) ? 128 : 256;
    int t = threadIdx.x;  // 256
    for (int i = t; i < m; i += 256) {
        sh[i] = (i < cnt) ? data[lo + i] : ~0ULL;
        pid[i] = (i < cnt) ? nidx[lo + i] : 0u;
    }
    __syncthreads();
    for (int k = 2; k <= m; k <<= 1) {
        for (int j = k >> 1; j > 0; j >>= 1) {
            for (int e = t; e < m; e += 256) {
                int p = e ^ j;
                if (p > e) {
                    u64 a = sh[e], c = sh[p];
                    bool up = ((e & k) == 0);
                    if (up ? (a > c) : (a < c)) {
                        sh[e] = c; sh[p] = a;
                        u32 tp = pid[e]; pid[e] = pid[p]; pid[p] = tp;
                    }
                }
            }
            __syncthreads();
        }
    }
    int i0 = 2 * t, i1 = 2 * t + 1;
    u32 f0 = (i0 < cnt) ? ((i0 == 0) ? 1u : (sh[i0] != sh[i0 - 1] ? 1u : 0u)) : 0u;
    u32 f1 = (i1 < cnt) ? (sh[i1] != sh[i1 - 1] ? 1u : 0u) : 0u;
    u32 s2 = f0 + f1;
    ts[t] = s2;
    __syncthreads();
    for (int o = 1; o < 256; o <<= 1) {
        u32 x = (t >= o) ? ts[t - o] : 0u;
        __syncthreads();
        ts[t] += x;
        __syncthreads();
    }
    u32 excl = ts[t] - s2;
    u32 tag = (u32)b << 16;
    if (i0 < cnt) { nidx[lo + i0] = pid[i0]; comb[lo + i0] = tag | (excl + f0); }
    if (i1 < cnt) { nidx[lo + i1] = pid[i1]; comb[lo + i1] = tag | (excl + f0 + f1); }
    if (t == 255) dcount[b] = ts[255];
}

// relabel with fused dscan: wave 0 shuffle-scans dcount (32/lane) into LDS,
// then streams colors[nidx[i]].
__global__ void k_relabel(const u32* __restrict__ comb, const u32* __restrict__ nidx,
                          const u32* __restrict__ dcount, int* __restrict__ colors, int n) {
    __shared__ u32 dbaseL[NKB];
    int t = threadIdx.x;  // 256
    if (t < 64) {
        u32 v[32]; u32 s = 0u;
#pragma unroll
        for (int i = 0; i < 32; ++i) { v[i] = dcount[t * 32 + i]; s += v[i]; }
        u32 ps = s;
#pragma unroll
        for (int o = 1; o < 64; o <<= 1) {
            u32 y = (u32)__shfl_up((int)ps, o, 64);
            if (t >= o) ps += y;
        }
        u32 run = ps - s;
#pragma unroll
        for (int i = 0; i < 32; ++i) { dbaseL[t * 32 + i] = run; run += v[i]; }
    }
    __syncthreads();
    int i = blockIdx.x * 256 + t;
    if (i >= n) return;
    u32 c = comb[i];
    colors[nidx[i]] = (int)(dbaseL[c >> 16] + (c & 0xFFFFu) - 1u);
}

// ---------------- launch ----------------

extern "C" void kernel_launch(void* const* d_in, const int* in_sizes, int n_in,
                              void* d_out, int out_size, void* d_ws, size_t ws_size,
                              hipStream_t stream) {
    const int* x = (const int*)d_in[0];
    const int* ei = (const int*)d_in[1];
    const int N = in_sizes[0];
    const int E = in_sizes[1] / 2;
    const int* row = ei;
    const int* col = ei + E;
    int* colors = (int*)d_out;

    const int ntiles = (E + TILE - 1) / TILE;

    char* ws = (char*)d_ws;
    size_t off = 0;
#define WS_ALLOC(T, name, bytes) T name = (T)(ws + off); off += (((size_t)(bytes)) + 255) & ~(size_t)255;
    WS_ALLOC(u32*, deg, (size_t)N * 4)
    WS_ALLOC(u32*, start, (size_t)N * 4)
    WS_ALLOC(u32*, adj, (size_t)E * 4)
    WS_ALLOC(u64*, keys, (size_t)N * 8)
    WS_ALLOC(u64*, sorted, (size_t)N * 8)
    WS_ALLOC(u32*, nidx, (size_t)N * 4)
    WS_ALLOC(u32*, comb, (size_t)N * 4)
    WS_ALLOC(u64*, lists, (size_t)3 * N * 8)              // packed class lists (not aliased)
    WS_ALLOC(u32*, bcnt5, (size_t)2 * NUM_IT * NKB * 4)   // histograms + zero-based cursors
    WS_ALLOC(u32*, boff, (NKB + 1) * 4)
    WS_ALLOC(u32*, dcount, NKB * 4)
    WS_ALLOC(u32*, bhist, 1024 * 4)
    WS_ALLOC(u32*, boffE, 1025 * 4)
    WS_ALLOC(u32*, bcur, 1024 * 4)
    WS_ALLOC(u32*, boffS, (SB + 1) * 4)
    WS_ALLOC(u32*, cnt3, 48 * 4)
    WS_ALLOC(u32*, thist, (size_t)ntiles * SB * 4)
    WS_ALLOC(u32*, tbase, (size_t)ntiles * SB * 4)
    // tail: adjt (E u32), partition scratch only
    u32* adjt = (u32*)(ws + off);
    const bool two_level = (off + (size_t)E * 4 <= ws_size);
#undef WS_ALLOC

    const int nB = (N + 255) / 256;
    const int nbuck = (N + 255) >> 8;      // fine buckets (782)
    const int nbS = (nbuck + 15) >> 4;     // super-buckets (49)
    const int kB = (N + KCH - 1) / KCH;
    const int sBk = (N + SCH - 1) / SCH;

    // CSR build (+fused degree classification in k_csr)
    k_init<<<nB, 256, 0, stream>>>(x, colors, bcnt5, bhist, cnt3, N, nbuck);
    k_chist<<<(E + HCH - 1) / HCH, 1024, 0, stream>>>(row, bhist, thist, E, nbuck);
    k_cscan<<<1, 256, 0, stream>>>(bhist, boffE, bcur, boffS, nbuck, nbS);
    if (two_level) {
        k_tscan<<<nbS, 256, 0, stream>>>(thist, boffS, tbase, ntiles);
        k_partA<<<ntiles, 256, 0, stream>>>(row, col, thist, tbase, adjt, E);
        k_partB<<<nbS * CHB, 256, 0, stream>>>(adjt, boffS, bcur, adj);
    } else {
        k_part<<<(E + PCHUNK - 1) / PCHUNK, 256, 0, stream>>>(row, col, bcur, adj, E, nbuck);
    }
    k_csr<<<nbuck, 1024, 0, stream>>>(adj, boffE, deg, start, lists, cnt3, N);

    for (int it = 0; it < NUM_IT; ++it) {
        u32* bcnt = bcnt5 + it * NKB;
        u32* bcur_it = bcnt5 + (NUM_IT + it) * NKB;
        k_hash<<<(N + 3) / 4, 256, 0, stream>>>(colors, deg, adj, lists, cnt3, keys, N);
        k_khist<<<kB, 256, 0, stream>>>(keys, bcnt, N);
        k_scatter<<<sBk, 1024, 0, stream>>>(keys, sorted, nidx, bcnt, bcur_it, boff, N);
        k_bsort<<<NKB, 256, 0, stream>>>(sorted, nidx, boff, comb, dcount);
        k_relabel<<<nB, 256, 0, stream>>>(comb, nidx, dcount, colors, N);
    }
}

// Round 14
// 593.419 us; speedup vs baseline: 1.1240x; 1.0643x over previous
//
#include <hip/hip_runtime.h>
#include <stdint.h>

typedef unsigned int u32;
typedef unsigned long long u64;

#define M1 2654435761u
#define M2 2246822519u
#define M3 3266489917u
#define M4 668265263u
#define NUM_IT 5
#define PCHUNK 16384   // fallback chunk
#define HCH 65536      // chist chunk (16 subtiles of 4096)
#define TILE 4096      // partition tile (partA)
#define PBCH 4096      // partB chunk
#define CCAP 16384
#define SB 64          // super-buckets (4096 nodes each; 49 used)
#define CHB 33         // partB chunks per super
#define NKB 2048       // key buckets (top 11 bits; avg 97.7, P(>256)~0)
#define KSH 53         // key shift for bucket id
#define SLOT 256       // fixed slots per bucket (b<<8 addressing)

// ---------------- setup ----------------

__global__ void k_init(const int* __restrict__ x, int* __restrict__ colors,
                       u32* __restrict__ cnt5, u32* __restrict__ bhist,
                       u32* __restrict__ cnt3, int n, int nbuck) {
    int i = blockIdx.x * blockDim.x + threadIdx.x;
    if (i < n) colors[i] = x[i];
    if (i < NUM_IT * NKB * 16) cnt5[i] = 0u;                   // padded bucket counters
    if (i >= 165888 && i < 165888 + nbuck) bhist[i - 165888] = 0u;
    if (i >= 168960 && i < 168960 + 48) cnt3[i - 168960] = 0u;
}

// fine-bucket edge histogram (row>>8) + per-4096-subtile super histogram (row>>12)
__global__ void k_chist(const int* __restrict__ row, u32* __restrict__ bhist,
                        u32* __restrict__ thist, int e, int nbuck) {
    __shared__ u32 fineh[1024];
    __shared__ u32 shist[16 * SB];
    int t = threadIdx.x;  // 1024
    fineh[t] = 0u;
    shist[t] = 0u;        // 16*64 == 1024
    __syncthreads();
    int c0 = blockIdx.x * HCH;
    int ce = c0 + HCH; if (ce > e) ce = e;
    int k = 0;
    for (int i = c0 + t; i < ce; i += 1024, ++k) {
        u32 r = (u32)row[i];
        atomicAdd(&fineh[r >> 8], 1u);
        atomicAdd(&shist[((k >> 2) << 6) | (r >> 12)], 1u);
    }
    __syncthreads();
    if (t < nbuck) {
        u32 v = fineh[t];
        if (v) atomicAdd(&bhist[t], v);
    }
    {
        int m = t >> 6;                     // subtile within chunk (0..15)
        if (c0 + m * TILE < e)
            thist[(size_t)(blockIdx.x * 16 + m) * SB + (t & 63)] = shist[t];
    }
}

// scan fine-bucket counts -> boffE/bcur; super offsets boffS
__global__ void k_cscan(const u32* __restrict__ bhist, u32* __restrict__ boffE,
                        u32* __restrict__ bcur, u32* __restrict__ boffS,
                        int nbuck, int nbS) {
    __shared__ u32 sh[256];
    u32 run = 0u;
    for (int base = 0; base < nbuck; base += 256) {
        int id = base + threadIdx.x;
        u32 x = (id < nbuck) ? bhist[id] : 0u;
        sh[threadIdx.x] = x;
        __syncthreads();
        for (int o = 1; o < 256; o <<= 1) {
            u32 t = (threadIdx.x >= (u32)o) ? sh[threadIdx.x - o] : 0u;
            __syncthreads();
            sh[threadIdx.x] += t;
            __syncthreads();
        }
        if (id < nbuck) {
            u32 excl = sh[threadIdx.x] - x + run;
            boffE[id] = excl;
            bcur[id] = excl;
            if ((id & 15) == 0) boffS[id >> 4] = excl;
        }
        u32 tot = sh[255];
        __syncthreads();
        run += tot;
    }
    if (threadIdx.x == 0) { boffE[nbuck] = run; boffS[nbS] = run; }
}

// per-super column scan of thist -> exact per-tile write base (NO atomics in partA)
__global__ void k_tscan(const u32* __restrict__ thist, const u32* __restrict__ boffS,
                        u32* __restrict__ tbase, int ntiles) {
    __shared__ u32 sh[256];
    int b = blockIdx.x;          // super bucket (grid = nbS)
    int t = threadIdx.x;
    u32 run = boffS[b];
    for (int base = 0; base < ntiles; base += 256) {
        int tile = base + t;
        u32 x = (tile < ntiles) ? thist[(size_t)tile * SB + b] : 0u;
        sh[t] = x;
        __syncthreads();
        for (int o = 1; o < 256; o <<= 1) {
            u32 y = (t >= o) ? sh[t - o] : 0u;
            __syncthreads();
            sh[t] += y;
            __syncthreads();
        }
        if (tile < ntiles) tbase[(size_t)tile * SB + b] = run + sh[t] - x;
        u32 tot = sh[255];
        __syncthreads();
        run += tot;
    }
}

// Pass A: single-pass LDS tile-reorder multisplit (hist comes free from thist)
__global__ void k_partA(const int* __restrict__ row, const int* __restrict__ col,
                        const u32* __restrict__ thist, const u32* __restrict__ tbase,
                        u32* __restrict__ adjt, int e) {
    __shared__ u32 vals[TILE];
    __shared__ unsigned char bkt[TILE];
    __shared__ u32 lbase[SB + 1], gbase[SB], cur[SB];
    int t = threadIdx.x;  // 256
    int c0 = blockIdx.x * TILE;
    int ce = c0 + TILE; if (ce > e) ce = e;
    if (t < SB) {
        gbase[t] = tbase[(size_t)blockIdx.x * SB + t];
        cur[t] = 0u;
        lbase[t] = thist[(size_t)blockIdx.x * SB + t];  // reuse as count first
    }
    __syncthreads();
    if (t == 0) {
        u32 run = 0u;
        for (int b = 0; b < SB; ++b) { u32 h = lbase[b]; lbase[b] = run; run += h; }
        lbase[SB] = run;
    }
    __syncthreads();
    for (int i = c0 + t; i < ce; i += 256) {
        u32 r = (u32)row[i];
        u32 s = r >> 12;
        u32 p = lbase[s] + atomicAdd(&cur[s], 1u);
        vals[p] = ((r & 4095u) << 18) | (u32)col[i];
        bkt[p] = (unsigned char)s;
    }
    __syncthreads();
    int cnt = ce - c0;
    for (int i = t; i < cnt; i += 256) {
        u32 b = (u32)bkt[i];
        adjt[gbase[b] + ((u32)i - lbase[b])] = vals[i];  // consecutive i -> coalesced
    }
}

// Pass B: LDS tile-reorder of each super-bucket chunk into its 16 fine buckets
__global__ void k_partB(const u32* __restrict__ adjt, const u32* __restrict__ boffS,
                        u32* __restrict__ ecur, u32* __restrict__ adj) {
    __shared__ u32 vals[PBCH];
    __shared__ u32 hist[16], lbase[17], gbase[16], cur[16];
    int s = blockIdx.x / CHB, c = blockIdx.x % CHB;
    u32 lo = boffS[s] + (u32)c * PBCH;
    u32 hi = boffS[s + 1];
    if (lo >= hi) return;
    if (hi > lo + PBCH) hi = lo + PBCH;
    int t = threadIdx.x;  // 256
    if (t < 16) hist[t] = 0u;
    __syncthreads();
    for (u32 i = lo + t; i < hi; i += 256)
        atomicAdd(&hist[(adjt[i] >> 26) & 15u], 1u);
    __syncthreads();
    if (t == 0) {
        u32 run = 0u;
        for (int b = 0; b < 16; ++b) { lbase[b] = run; run += hist[b]; }
        lbase[16] = run;
    }
    __syncthreads();
    if (t < 16) {
        u32 h = hist[t];
        gbase[t] = h ? atomicAdd(&ecur[s * 16 + t], h) : 0u;
        cur[t] = 0u;
    }
    __syncthreads();
    for (u32 i = lo + t; i < hi; i += 256) {
        u32 v = adjt[i];
        u32 b = (v >> 26) & 15u;
        vals[lbase[b] + atomicAdd(&cur[b], 1u)] = v;
    }
    __syncthreads();
    u32 cnt = hi - lo;
    for (u32 i = t; i < cnt; i += 256) {
        u32 v = vals[i];
        u32 b = (v >> 26) & 15u;
        adj[gbase[b] + (i - lbase[b])] = v & 0x03FFFFFFu;  // (row&255)<<18 | col
    }
}

// fallback single-level partition (only if ws too small)
__global__ void k_part(const int* __restrict__ row, const int* __restrict__ col,
                       u32* __restrict__ bcur, u32* __restrict__ adjp, int e, int nbuck) {
    __shared__ u32 hist[1024], base[1024], cur[1024];
    int c0 = blockIdx.x * PCHUNK;
    int cend = c0 + PCHUNK; if (cend > e) cend = e;
    for (int t = threadIdx.x; t < nbuck; t += 256) hist[t] = 0u;
    __syncthreads();
    for (int i = c0 + threadIdx.x; i < cend; i += 256)
        atomicAdd(&hist[((u32)row[i]) >> 8], 1u);
    __syncthreads();
    for (int t = threadIdx.x; t < nbuck; t += 256) {
        u32 h = hist[t];
        base[t] = h ? atomicAdd(&bcur[t], h) : 0u;
        cur[t] = 0u;
    }
    __syncthreads();
    for (int i = c0 + threadIdx.x; i < cend; i += 256) {
        u32 r = (u32)row[i];
        u32 b = r >> 8;
        u32 local = atomicAdd(&cur[b], 1u);
        adjp[base[b] + local] = ((r & 255u) << 18) | (u32)col[i];
    }
}

// ---------------- CSR: fused, 1024 threads, in-place permute ----------------
// Scattered-4B floor (~48 µs) resists occupancy (14%->52% same time, r11),
// split (write-amp 7.4x, r9), and chain-shortening. Parked.
__global__ void k_csr(u32* __restrict__ adj, const u32* __restrict__ boffE,
                      u32* __restrict__ deg, u32* __restrict__ start,
                      u64* __restrict__ lists, u32* __restrict__ cnt3, int n) {
    __shared__ u32 buf[CCAP];
    __shared__ u32 cnt[256], cur[256];
    __shared__ u32 wsum[4];
    __shared__ u32 ch[3], cbase[3];
    int b = blockIdx.x;
    int v0 = b << 8;
    u32 bs = boffE[b], be = boffE[b + 1];
    int c = (int)(be - bs);
    if (c > CCAP) c = CCAP;
    int t = threadIdx.x;  // 1024
    int lane = t & 63, w = t >> 6;
    if (t < 256) cnt[t] = 0u;
    if (t < 3) ch[t] = 0u;
    for (int i = t; i < c; i += 1024) buf[i] = adj[bs + i];
    __syncthreads();
    for (int i = t; i < c; i += 1024)
        atomicAdd(&cnt[buf[i] >> 18], 1u);
    __syncthreads();
    u32 myc = 0u, ps = 0u;
    if (t < 256) {
        myc = cnt[t];
        ps = myc;
#pragma unroll
        for (int o = 1; o < 64; o <<= 1) {
            u32 y = (u32)__shfl_up((int)ps, o, 64);
            if (lane >= o) ps += y;
        }
        if (lane == 63) wsum[w] = ps;
    }
    __syncthreads();
    u32 cls = 0u, crk = 0u, myStart = 0u;
    int v = v0 + t;
    if (t < 256) {
        u32 wb = 0u;
        for (int j = 0; j < w; ++j) wb += wsum[j];
        u32 excl = wb + ps - myc;
        myStart = bs + excl;
        if (v < n) {
            deg[v] = myc;
            start[v] = myStart;
            cls = (myc <= 32u) ? 0u : ((myc <= 64u) ? 1u : 2u);
            crk = atomicAdd(&ch[cls], 1u);
        }
        cur[t] = myStart;
    }
    __syncthreads();
    if (t < 3) cbase[t] = ch[t] ? atomicAdd(&cnt3[t * 16], ch[t]) : 0u;
    __syncthreads();
    if (t < 256 && v < n) {
        u32 dcl = myc > 0x3FFFu ? 0x3FFFu : myc;
        lists[cls * (size_t)n + cbase[cls] + crk] =
            ((u64)((dcl << 18) | (u32)v) << 32) | (u64)myStart;   // register — no race
    }
    for (int i = t; i < c; i += 1024) {
        u32 p = buf[i];
        u32 q = atomicAdd(&cur[p >> 18], 1u);
        adj[q] = p & 0x3FFFFu;   // in-place: lines L2-warm from staging read
    }
}

// ---------------- hash: 4-elem/lane packed bitonic + packed lists ----------------
// At its gather/issue floor (~46 µs; rounds 1-8 explored ILP, persistence,
// fat blocks, reg-packing, chain-shortening). Parked.

__device__ __forceinline__ void ce_reg(u32& a, u32& b, bool up) {
    u32 mn = a < b ? a : b, mx = a < b ? b : a;
    a = up ? mn : mx; b = up ? mx : mn;
}
__device__ __forceinline__ void ce_shf(u32& a, int o, bool tm) {
    u32 ot = (u32)__shfl_xor((int)a, o, 64);
    u32 mn = a < ot ? a : ot, mx = a < ot ? ot : a;
    a = tm ? mn : mx;
}
#define CE_SH4(o, tm) { ce_shf(c0, o, tm); ce_shf(c1, o, tm); ce_shf(c2, o, tm); ce_shf(c3, o, tm); }
#define CE_RG4(up)    { ce_reg(c0, c2, up); ce_reg(c1, c3, up); ce_reg(c0, c1, up); ce_reg(c2, c3, up); }

__global__ void k_hash(const int* __restrict__ colors, const u32* __restrict__ deg,
                       const u32* __restrict__ adj,
                       const u64* __restrict__ lists, const u32* __restrict__ cnt3,
                       u64* __restrict__ keys, int n) {
    int lane = threadIdx.x & 63;
    int wid = (int)((blockIdx.x * 256u + threadIdx.x) >> 6);
    u32 nA = cnt3[0], nBc = cnt3[16], nCc = cnt3[32];
    int octA = (int)((nA + 7u) >> 3);
    int quadB = (int)((nBc + 3u) >> 2);
    if (wid < octA) {
        // -------- A: 8 nodes/wave, 8 lanes/node, 32-slot sort --------
        int s = lane & 7;
        int li = 8 * wid + (lane >> 3);
        int node = -1;
        u32 c0 = 0xFFFFFFFFu, c1 = 0xFFFFFFFFu, c2 = 0xFFFFFFFFu, c3 = 0xFFFFFFFFu;
        u32 e0 = 4u * (u32)s;
        if (li < (int)nA) {
            u64 pk = lists[li];
            u32 st = (u32)pk;
            u32 hi = (u32)(pk >> 32);
            u32 d = hi >> 18;
            node = (int)(hi & 0x3FFFFu);
            if (e0 + 0u < d) c0 = (u32)colors[adj[st + e0 + 0u]];
            if (e0 + 1u < d) c1 = (u32)colors[adj[st + e0 + 1u]];
            if (e0 + 2u < d) c2 = (u32)colors[adj[st + e0 + 2u]];
            if (e0 + 3u < d) c3 = (u32)colors[adj[st + e0 + 3u]];
        }
        bool s1 = (s & 1) == 0, s2 = (s & 2) == 0, s4 = (s & 4) == 0;
        // k=2
        ce_reg(c0, c1, true); ce_reg(c2, c3, false);
        // k=4
        CE_RG4(s1)
        // k=8
        CE_SH4(1, s1 == s2)
        CE_RG4(s2)
        // k=16
        CE_SH4(2, s2 == s4)
        CE_SH4(1, s1 == s4)
        CE_RG4(s4)
        // k=32 (final ascending merge)
        CE_SH4(4, s4)
        CE_SH4(2, s2)
        CE_SH4(1, s1)
        CE_RG4(true)
        // hash: pos = e = 4s + r
        u32 a1 = e0 * M1, a3 = e0 * M3;
        u32 v = (c0 + 1u) * (a1 + M2)           + (c1 + 1u) * (a1 + 1u * M1 + M2)
              + (c2 + 1u) * (a1 + 2u * M1 + M2) + (c3 + 1u) * (a1 + 3u * M1 + M2);
        u32 w = (c0 + 1u) * (a3 + M4)           + (c1 + 1u) * (a3 + 1u * M3 + M4)
              + (c2 + 1u) * (a3 + 2u * M3 + M4) + (c3 + 1u) * (a3 + 3u * M3 + M4);
#pragma unroll
        for (int o = 1; o < 8; o <<= 1) {
            v += (u32)__shfl_xor((int)v, o, 64);
            w += (u32)__shfl_xor((int)w, o, 64);
        }
        if (s == 0 && node >= 0) {
            u32 own = (u32)colors[node] + 1u;
            keys[node] = ((u64)(v * M2 + own * M1) << 32) | (u64)(w * M4 + own * M3);
        }
    } else if (wid < octA + quadB) {
        // -------- B: 4 nodes/wave, 16 lanes/node, 64-slot sort --------
        int s = lane & 15;
        int li = 4 * (wid - octA) + (lane >> 4);
        int node = -1;
        u32 c0 = 0xFFFFFFFFu, c1 = 0xFFFFFFFFu, c2 = 0xFFFFFFFFu, c3 = 0xFFFFFFFFu;
        u32 e0 = 4u * (u32)s;
        if (li < (int)nBc) {
            u64 pk = lists[(size_t)n + (u32)li];
            u32 st = (u32)pk;
            u32 hi = (u32)(pk >> 32);
            u32 d = hi >> 18;
            node = (int)(hi & 0x3FFFFu);
            if (e0 + 0u < d) c0 = (u32)colors[adj[st + e0 + 0u]];
            if (e0 + 1u < d) c1 = (u32)colors[adj[st + e0 + 1u]];
            if (e0 + 2u < d) c2 = (u32)colors[adj[st + e0 + 2u]];
            if (e0 + 3u < d) c3 = (u32)colors[adj[st + e0 + 3u]];
        }
        bool s1 = (s & 1) == 0, s2 = (s & 2) == 0, s4 = (s & 4) == 0, s8 = (s & 8) == 0;
        // k=2
        ce_reg(c0, c1, true); ce_reg(c2, c3, false);
        // k=4
        CE_RG4(s1)
        // k=8
        CE_SH4(1, s1 == s2)
        CE_RG4(s2)
        // k=16
        CE_SH4(2, s2 == s4)
        CE_SH4(1, s1 == s4)
        CE_RG4(s4)
        // k=32
        CE_SH4(4, s4 == s8)
        CE_SH4(2, s2 == s8)
        CE_SH4(1, s1 == s8)
        CE_RG4(s8)
        // k=64 (final ascending merge)
        CE_SH4(8, s8)
        CE_SH4(4, s4)
        CE_SH4(2, s2)
        CE_SH4(1, s1)
        CE_RG4(true)
        u32 a1 = e0 * M1, a3 = e0 * M3;
        u32 v = (c0 + 1u) * (a1 + M2)           + (c1 + 1u) * (a1 + 1u * M1 + M2)
              + (c2 + 1u) * (a1 + 2u * M1 + M2) + (c3 + 1u) * (a1 + 3u * M1 + M2);
        u32 w = (c0 + 1u) * (a3 + M4)           + (c1 + 1u) * (a3 + 1u * M3 + M4)
              + (c2 + 1u) * (a3 + 2u * M3 + M4) + (c3 + 1u) * (a3 + 3u * M3 + M4);
#pragma unroll
        for (int o = 1; o < 16; o <<= 1) {
            v += (u32)__shfl_xor((int)v, o, 64);
            w += (u32)__shfl_xor((int)w, o, 64);
        }
        if (s == 0 && node >= 0) {
            u32 own = (u32)colors[node] + 1u;
            keys[node] = ((u64)(v * M2 + own * M1) << 32) | (u64)(w * M4 + own * M3);
        }
    } else if (wid < octA + quadB + (int)nCc) {
        // -------- C: d>64, strided O(d^2) fallback (rare) --------
        u64 pk = lists[2u * (size_t)n + (u32)(wid - octA - quadB)];
        int node = (int)((u32)(pk >> 32) & 0x3FFFFu);
        u32 st = (u32)pk;
        u32 d = deg[node];                   // exact degree (packed field clamps)
        u32 v = 0u, w = 0u;
        for (u32 i = (u32)lane; i < d; i += 64u) {
            u32 ci = (u32)colors[adj[st + i]];
            u32 pos = 0u;
            for (u32 j = 0; j < d; ++j) {
                u32 cj = (u32)colors[adj[st + j]];
                pos += (cj < ci) || (cj == ci && j < i);
            }
            v += (ci + 1u) * (pos * M1 + M2);
            w += (ci + 1u) * (pos * M3 + M4);
        }
        for (int o = 32; o > 0; o >>= 1) {
            v += (u32)__shfl_xor((int)v, o, 64);
            w += (u32)__shfl_xor((int)w, o, 64);
        }
        if (lane == 0) {
            u32 own = (u32)colors[node] + 1u;
            keys[node] = ((u64)(v * M2 + own * M1) << 32) | (u64)(w * M4 + own * M3);
        }
    }
}

// ---------------- relabel pipeline: slotted buckets (round-13 post-mortem) ----------------
// khist/boff/scan machinery DELETED: each bucket owns a fixed 256-slot
// region (b<<8). Scatter is one-thread-per-key with padded (64B/line)
// per-bucket counters -> full grid parallelism (was 25-49 blocks).
// Bucket-major + in-bucket sort == global sorted-key order, so compact ids
// still match jnp.unique exactly.

// scatter (key, node-id) directly into bucket slots
__global__ void k_scatter(const u64* __restrict__ keys, u64* __restrict__ out,
                          u32* __restrict__ nout, u32* __restrict__ cnt, int n) {
    int i = blockIdx.x * 256 + threadIdx.x;
    if (i >= n) return;
    u64 k = keys[i];
    u32 b = (u32)(k >> KSH);
    u32 r = atomicAdd(&cnt[b * 16], 1u);   // padded: one 64B line per counter
    if (r < (u32)SLOT) {
        u32 p = (b << 8) + r;
        out[p] = k;
        nout[p] = (u32)i;
    }
}

// Adaptive-width (128 or 256) bitonic key+payload sort per bucket + fused
// distinct scan. Poisson(97.7): 128-slot network covers most buckets.
// Emits comb = localD (1-based) per slot and permuted node ids in place.
__global__ void k_bsort(u64* __restrict__ data, u32* __restrict__ nidx,
                        const u32* __restrict__ cnt,
                        u32* __restrict__ comb, u32* __restrict__ dcount) {
    __shared__ u64 sh[256];
    __shared__ u32 pid[256];
    __shared__ u32 ts[256];
    int b = blockIdx.x;
    u32 lo = (u32)b << 8;
    int c = (int)cnt[b * 16];
    if (c > SLOT) c = SLOT;
    int m = (c <= 128) ? 128 : 256;
    int t = threadIdx.x;  // 256
    for (int i = t; i < m; i += 256) {
        sh[i] = (i < c) ? data[lo + i] : ~0ULL;
        pid[i] = (i < c) ? nidx[lo + i] : 0u;
    }
    __syncthreads();
    for (int k = 2; k <= m; k <<= 1) {
        for (int j = k >> 1; j > 0; j >>= 1) {
            for (int e = t; e < m; e += 256) {
                int p = e ^ j;
                if (p > e) {
                    u64 a = sh[e], cc = sh[p];
                    bool up = ((e & k) == 0);
                    if (up ? (a > cc) : (a < cc)) {
                        sh[e] = cc; sh[p] = a;
                        u32 tp = pid[e]; pid[e] = pid[p]; pid[p] = tp;
                    }
                }
            }
            __syncthreads();
        }
    }
    int i0 = 2 * t, i1 = 2 * t + 1;
    u32 f0 = (i0 < c) ? ((i0 == 0) ? 1u : (sh[i0] != sh[i0 - 1] ? 1u : 0u)) : 0u;
    u32 f1 = (i1 < c) ? (sh[i1] != sh[i1 - 1] ? 1u : 0u) : 0u;
    u32 s2 = f0 + f1;
    ts[t] = s2;
    __syncthreads();
    for (int o = 1; o < 256; o <<= 1) {
        u32 x = (t >= o) ? ts[t - o] : 0u;
        __syncthreads();
        ts[t] += x;
        __syncthreads();
    }
    u32 excl = ts[t] - s2;
    if (i0 < c) { nidx[lo + i0] = pid[i0]; comb[lo + i0] = excl + f0; }
    if (i1 < c) { nidx[lo + i1] = pid[i1]; comb[lo + i1] = excl + f0 + f1; }
    if (t == 255) dcount[b] = ts[255];
}

// relabel: one block per bucket. Block computes dbase[b] = sum dcount[0..b)
// cooperatively (<=8 loads/thread, L2-hot), then writes its <=256 colors.
__global__ void k_relabel(const u32* __restrict__ comb, const u32* __restrict__ nidx,
                          const u32* __restrict__ dcount, const u32* __restrict__ cnt,
                          int* __restrict__ colors) {
    __shared__ u32 red[256];
    int b = blockIdx.x;
    int t = threadIdx.x;  // 256
    u32 partial = 0u;
    for (int j = t; j < b; j += 256) partial += dcount[j];
    red[t] = partial;
    __syncthreads();
    for (int o = 128; o > 0; o >>= 1) {
        if (t < o) red[t] += red[t + o];
        __syncthreads();
    }
    u32 dbase = red[0];
    u32 c = cnt[b * 16];
    if (c > (u32)SLOT) c = (u32)SLOT;
    u32 lo = (u32)b << 8;
    for (u32 i = (u32)t; i < c; i += 256u)
        colors[nidx[lo + i]] = (int)(dbase + comb[lo + i] - 1u);
}

// ---------------- launch ----------------

extern "C" void kernel_launch(void* const* d_in, const int* in_sizes, int n_in,
                              void* d_out, int out_size, void* d_ws, size_t ws_size,
                              hipStream_t stream) {
    const int* x = (const int*)d_in[0];
    const int* ei = (const int*)d_in[1];
    const int N = in_sizes[0];
    const int E = in_sizes[1] / 2;
    const int* row = ei;
    const int* col = ei + E;
    int* colors = (int*)d_out;

    const int ntiles = (E + TILE - 1) / TILE;

    char* ws = (char*)d_ws;
    size_t off = 0;
#define WS_ALLOC(T, name, bytes) T name = (T)(ws + off); off += (((size_t)(bytes)) + 255) & ~(size_t)255;
    WS_ALLOC(u32*, deg, (size_t)N * 4)
    WS_ALLOC(u32*, start, (size_t)N * 4)
    WS_ALLOC(u32*, adj, (size_t)E * 4)
    WS_ALLOC(u64*, keys, (size_t)N * 8)
    WS_ALLOC(u64*, sorted, (size_t)NKB * SLOT * 8)        // slotted buckets (4MB)
    WS_ALLOC(u32*, nidx, (size_t)NKB * SLOT * 4)          // slotted (2MB)
    WS_ALLOC(u32*, comb, (size_t)NKB * SLOT * 4)          // slotted localD (2MB)
    WS_ALLOC(u64*, lists, (size_t)3 * N * 8)              // packed class lists
    WS_ALLOC(u32*, cnt5, (size_t)NUM_IT * NKB * 16 * 4)   // padded bucket counters
    WS_ALLOC(u32*, dcount, NKB * 4)
    WS_ALLOC(u32*, bhist, 1024 * 4)
    WS_ALLOC(u32*, boffE, 1025 * 4)
    WS_ALLOC(u32*, bcur, 1024 * 4)
    WS_ALLOC(u32*, boffS, (SB + 1) * 4)
    WS_ALLOC(u32*, cnt3, 48 * 4)
    WS_ALLOC(u32*, thist, (size_t)ntiles * SB * 4)
    WS_ALLOC(u32*, tbase, (size_t)ntiles * SB * 4)
    // tail: adjt (E u32), partition scratch only
    u32* adjt = (u32*)(ws + off);
    const bool two_level = (off + (size_t)E * 4 <= ws_size);
#undef WS_ALLOC

    const int nB = (N + 255) / 256;
    const int nbuck = (N + 255) >> 8;      // fine buckets (782)
    const int nbS = (nbuck + 15) >> 4;     // super-buckets (49)

    // CSR build (+fused degree classification in k_csr)
    k_init<<<nB, 256, 0, stream>>>(x, colors, cnt5, bhist, cnt3, N, nbuck);
    k_chist<<<(E + HCH - 1) / HCH, 1024, 0, stream>>>(row, bhist, thist, E, nbuck);
    k_cscan<<<1, 256, 0, stream>>>(bhist, boffE, bcur, boffS, nbuck, nbS);
    if (two_level) {
        k_tscan<<<nbS, 256, 0, stream>>>(thist, boffS, tbase, ntiles);
        k_partA<<<ntiles, 256, 0, stream>>>(row, col, thist, tbase, adjt, E);
        k_partB<<<nbS * CHB, 256, 0, stream>>>(adjt, boffS, bcur, adj);
    } else {
        k_part<<<(E + PCHUNK - 1) / PCHUNK, 256, 0, stream>>>(row, col, bcur, adj, E, nbuck);
    }
    k_csr<<<nbuck, 1024, 0, stream>>>(adj, boffE, deg, start, lists, cnt3, N);

    for (int it = 0; it < NUM_IT; ++it) {
        u32* cnt_it = cnt5 + (size_t)it * NKB * 16;
        k_hash<<<(N + 3) / 4, 256, 0, stream>>>(colors, deg, adj, lists, cnt3, keys, N);
        k_scatter<<<nB, 256, 0, stream>>>(keys, sorted, nidx, cnt_it, N);
        k_bsort<<<NKB, 256, 0, stream>>>(sorted, nidx, cnt_it, comb, dcount);
        k_relabel<<<NKB, 256, 0, stream>>>(comb, nidx, dcount, cnt_it, colors);
    }
}